// Round 10
// baseline (1638.602 us; speedup 1.0000x reference)
//
// ===========================================================================
// R23 — R19 kernel verbatim (the known-replay-safe best, 1215us) with ONLY
// tile-size changes: TL 128->64 on CI<=64 MODE0 convs (LDS 58.9K->42.1K ->
// 3 blocks/CU; K=1 layers -> 24.7K -> 6 blocks/CU) and us2 TL 128->64
// (65.7K->49.3K -> 3 blocks/CU). Per-output accumulation order unchanged.
// R22's acc-init ADDINIT cross-dispatch RMW abandoned (graph-replay
// divergence); dr2/2to1 keep R19's epilogue F_ADD split which passed the
// replay tripwire. VQ = R15 dot-form split (unchanged).
// ===========================================================================
#include <hip/hip_runtime.h>
#include <stdint.h>

#define F_WT     1
#define F_STATS  2
#define F_BIAS   4
#define F_INBN   8
#define F_INRELU 16
#define F_INB    32
#define F_INBBN  64
#define F_ADD    128
#define F_ADDBN  256

// ---------------------------------------------------------------------------
// Tiled conv, CR outputs/thread in channel dim.
// MODE 0: stride-1 (PAD template), WT: ConvTranspose (I,O,K) flipped.
// MODE 1: stride-2 downsample K=2. MODE 2: stride-2 transposed upsample K=2.
// 256 thr = NCG(=COB/CR) co-groups x LT(=256/NCG) l-groups, TLT=TL/LT.
// ---------------------------------------------------------------------------
template<int CI, int CO, int K, int MODE, int TL, int COB, int CR, int PAD,
         int FLAGS>
__global__ __launch_bounds__(256)
void conv_rM(const float* __restrict__ xa, const float2* __restrict__ sca,
             const float* __restrict__ xb, const float2* __restrict__ scb,
             const float* __restrict__ w,  const float* __restrict__ bias,
             const float* __restrict__ addsrc, const float2* __restrict__ scadd,
             double* __restrict__ stats, float* __restrict__ yout,
             int Lin, int Lout, int cis, int wci)
{
    constexpr int NCG  = COB / CR;          // co groups
    constexpr int LT   = 256 / NCG;         // l groups
    constexpr int TLT  = TL / LT;           // outputs per thread per co
    constexpr int SPAN = (MODE == 0) ? (TL + K - 1)
                       : (MODE == 1) ? ((TL - 1) * 2 + K)
                       : (TL / 2);
    constexpr int SPANP = (SPAN + 3) & ~3;
    constexpr int WR    = K * CR;
    constexpr int WRP   = (WR + 3) & ~3;
    constexpr int WROW  = CI * WRP + 4;     // +4 float stagger per cog
    constexpr int XR    = (MODE == 0) ? (TLT + K - 1)
                        : (MODE == 1) ? ((TLT - 1) * 2 + K)
                        : ((TLT + 1) / 2);
    // aligned-window shift: x0 = ltile*stride - PAD; ALN makes loads 16B-aligned
    constexpr int ALN  = (MODE == 0) ? ((4 - (PAD & 3)) & 3) : 0;
    constexpr int NW   = (SPAN + ALN + 3) / 4;     // f4 loads per row
    constexpr int NTASK = CI * NW;
    constexpr int PT    = (NTASK + 255) / 256;
    constexpr bool F4ST = (ALN == 0) && (SPAN % 4 == 0);
    constexpr int WNT   = NCG * CI * WR;
    constexpr int WPT   = (WNT + 255) / 256;

    __shared__ float xs[CI * SPANP];
    __shared__ float wl[NCG * WROW];

    const int tid    = threadIdx.x;
    const int ltile  = blockIdx.x;
    const int n      = blockIdx.y;
    const int coBase = blockIdx.z * COB;

    // ---- weights -> LDS (two-phase batched) ----
    {
        float wvv[WPT];
#pragma unroll
        for (int p = 0; p < WPT; ++p) {
            int i = tid + p * 256;
            float v = 0.f;
            if (i < WNT) {
                int cogi = i / (CI * WR);
                int rem  = i - cogi * (CI * WR);
                int ci   = rem / WR;
                int rem2 = rem - ci * WR;
                int k    = rem2 / CR;
                int cr   = rem2 - k * CR;
                int co   = coBase + cogi * CR + cr;
                int src;
                if (FLAGS & F_WT)   src = (ci * CO + co) * K + (K - 1 - k);
                else if (MODE == 2) src = (ci * CO + co) * K + k;
                else                src = (co * wci + ci) * K + k;
                v = w[src];
            }
            wvv[p] = v;
        }
#pragma unroll
        for (int p = 0; p < WPT; ++p) {
            int i = tid + p * 256;
            if (i < WNT) {
                int cogi = i / (CI * WR);
                int rem  = i - cogi * (CI * WR);
                int ci   = rem / WR;
                int rem2 = rem - ci * WR;
                int k    = rem2 / CR;
                int cr   = rem2 - k * CR;
                wl[cogi * WROW + ci * WRP + k * CR + cr] = wvv[p];
            }
        }
    }

    // ---- x -> LDS, two-phase: batched f4 loads, then transform+write ----
    int x0;
    if (MODE == 0)      x0 = ltile * TL - PAD;
    else if (MODE == 1) x0 = ltile * TL * 2;
    else                x0 = ltile * (TL / 2);
    const int xw0 = x0 - ALN;               // aligned window start

    {
        float4 va[PT];
        float4 vb[PT];
#pragma unroll
        for (int p = 0; p < PT; ++p) {
            int i = tid + p * 256;
            float4 v = make_float4(0.f, 0.f, 0.f, 0.f);
            float4 u = make_float4(0.f, 0.f, 0.f, 0.f);
            if (i < NTASK) {
                int ci  = i / NW;
                int q   = i - ci * NW;
                int xl4 = xw0 + 4 * q;
                size_t rb = ((size_t)n * cis + ci) * (size_t)Lin;
                if (xl4 >= 0 && xl4 + 3 < Lin) {
                    v = *(const float4*)(xa + rb + xl4);
                    if (FLAGS & F_INB) u = *(const float4*)(xb + rb + xl4);
                } else {
                    float* pv = (float*)&v;
                    float* pu = (float*)&u;
#pragma unroll
                    for (int t = 0; t < 4; ++t) {
                        int xl = xl4 + t;
                        if (xl >= 0 && xl < Lin) {
                            pv[t] = xa[rb + xl];
                            if (FLAGS & F_INB) pu[t] = xb[rb + xl];
                        }
                    }
                }
            }
            va[p] = v;
            if (FLAGS & F_INB) vb[p] = u;
        }
#pragma unroll
        for (int p = 0; p < PT; ++p) {
            int i = tid + p * 256;
            if (i < NTASK) {
                int ci = i / NW;
                int q  = i - ci * NW;
                int xl4 = xw0 + 4 * q;
                float4 v = va[p];
                float* pv = (float*)&v;
                if (FLAGS & F_INBN) {
                    float2 t = sca[ci];
#pragma unroll
                    for (int e = 0; e < 4; ++e) pv[e] = pv[e] * t.x + t.y;
                }
                if (FLAGS & F_INRELU) {
#pragma unroll
                    for (int e = 0; e < 4; ++e) pv[e] = fmaxf(pv[e], 0.f);
                }
                if (FLAGS & F_INB) {
                    float4 u = vb[p];
                    float* pu = (float*)&u;
                    if (FLAGS & F_INBBN) {
                        float2 t = scb[ci];
#pragma unroll
                        for (int e = 0; e < 4; ++e) {
                            float uu = pu[e] * t.x + t.y;
                            pv[e] += uu;
                        }
                    } else {
#pragma unroll
                        for (int e = 0; e < 4; ++e) pv[e] += pu[e];
                    }
                }
                // zero-padding: transforms must NOT touch OOB slots.
#pragma unroll
                for (int e = 0; e < 4; ++e) {
                    int xl = xl4 + e;
                    if (xl < 0 || xl >= Lin) pv[e] = 0.f;
                }
                if constexpr (F4ST) {
                    *(float4*)&xs[ci * SPANP + 4 * q] = v;
                } else {
#pragma unroll
                    for (int t = 0; t < 4; ++t) {
                        int s = 4 * q + t - ALN;
                        if (s >= 0 && s < SPAN) xs[ci * SPANP + s] = pv[t];
                    }
                }
            }
        }
    }
    __syncthreads();

    const int cog   = tid / LT;
    const int lg    = tid % LT;
    const int co0   = coBase + cog * CR;
    const int loOff = lg * TLT;
    const int xoff  = (MODE == 1) ? loOff * 2
                    : (MODE == 2) ? (loOff >> 1) : loOff;

    float acc[CR][TLT];
#pragma unroll
    for (int cr = 0; cr < CR; ++cr) {
        float b = (FLAGS & F_BIAS) ? bias[co0 + cr] : 0.f;
#pragma unroll
        for (int j = 0; j < TLT; ++j) acc[cr][j] = b;
    }

    float xA[XR], xB[XR], wA[WR], wB[WR];

    auto ldx = [&](float* dst, int c) {
        const int base = c * SPANP + xoff;
#pragma unroll
        for (int g = 0; g < XR; g += 4) {
            const float* p = &xs[base + g];
#pragma unroll
            for (int t = 0; t < 4; ++t)
                if (g + t < XR) dst[g + t] = p[t];
        }
    };
    auto ldw = [&](float* dst, int c) {
        const float* q = &wl[cog * WROW + c * WRP];
#pragma unroll
        for (int t = 0; t < WR; ++t) dst[t] = q[t];
    };
    auto dofma = [&](const float* xv, const float* wv) {
        if (MODE == 2) {
#pragma unroll
            for (int j = 0; j < TLT; ++j)
#pragma unroll
                for (int cr = 0; cr < CR; ++cr)
                    acc[cr][j] += wv[(j & 1) * CR + cr] * xv[j >> 1];
        } else {
#pragma unroll
            for (int k = 0; k < K; ++k)
#pragma unroll
                for (int j = 0; j < TLT; ++j)
#pragma unroll
                    for (int cr = 0; cr < CR; ++cr)
                        acc[cr][j] += wv[k * CR + cr]
                                    * xv[((MODE == 1) ? 2 * j : j) + k];
        }
    };

    if constexpr (K <= 3) {
        // register-double-buffered ci loop (CI even, >= 32)
        ldx(xA, 0); ldw(wA, 0);
        for (int ci = 0; ci + 2 < CI; ci += 2) {
            ldx(xB, ci + 1); ldw(wB, ci + 1);
            dofma(xA, wA);
            ldx(xA, ci + 2); ldw(wA, ci + 2);
            dofma(xB, wB);
        }
        ldx(xB, CI - 1); ldw(wB, CI - 1);
        dofma(xA, wA);
        dofma(xB, wB);
    } else {
#pragma unroll 2
        for (int ci = 0; ci < CI; ++ci) {
            ldx(xA, ci); ldw(wA, ci);
            dofma(xA, wA);
        }
    }

    // ---- epilogue: output-side add (opt BN), store, stats ----
    const int lo0 = ltile * TL + loOff;
#pragma unroll
    for (int cr = 0; cr < CR; ++cr) {
        size_t ob = ((size_t)n * CO + (co0 + cr)) * (size_t)Lout + lo0;
        if (FLAGS & F_ADD) {
            float2 t = (FLAGS & F_ADDBN) ? scadd[co0 + cr] : make_float2(1.f, 0.f);
            if constexpr (TLT % 4 == 0) {
#pragma unroll
                for (int jv = 0; jv < TLT / 4; ++jv) {
                    float4 av = ((const float4*)(addsrc + ob))[jv];
                    float* a4 = &acc[cr][jv * 4];
                    if (FLAGS & F_ADDBN) {
                        a4[0] += av.x * t.x + t.y; a4[1] += av.y * t.x + t.y;
                        a4[2] += av.z * t.x + t.y; a4[3] += av.w * t.x + t.y;
                    } else {
                        a4[0] += av.x; a4[1] += av.y; a4[2] += av.z; a4[3] += av.w;
                    }
                }
            } else {
#pragma unroll
                for (int j = 0; j < TLT; ++j) {
                    float a = addsrc[ob + j];
                    acc[cr][j] += (FLAGS & F_ADDBN) ? (a * t.x + t.y) : a;
                }
            }
        }
        if constexpr (TLT % 4 == 0) {
#pragma unroll
            for (int jv = 0; jv < TLT / 4; ++jv) {
                float4 sv = make_float4(acc[cr][jv*4+0], acc[cr][jv*4+1],
                                        acc[cr][jv*4+2], acc[cr][jv*4+3]);
                ((float4*)(yout + ob))[jv] = sv;
            }
        } else {
#pragma unroll
            for (int j = 0; j < TLT; ++j) yout[ob + j] = acc[cr][j];
        }
    }

    if (FLAGS & F_STATS) {
        float s1[CR], s2[CR];
#pragma unroll
        for (int cr = 0; cr < CR; ++cr) {
            s1[cr] = 0.f; s2[cr] = 0.f;
#pragma unroll
            for (int j = 0; j < TLT; ++j) {
                s1[cr] += acc[cr][j];
                s2[cr] += acc[cr][j] * acc[cr][j];
            }
        }
#pragma unroll
        for (int m = 1; m < LT; m <<= 1) {
#pragma unroll
            for (int cr = 0; cr < CR; ++cr) {
                s1[cr] += __shfl_xor(s1[cr], m, 64);
                s2[cr] += __shfl_xor(s2[cr], m, 64);
            }
        }
        if ((tid & (LT - 1)) == 0) {
#pragma unroll
            for (int cr = 0; cr < CR; ++cr) {
                atomicAdd(&stats[co0 + cr],      (double)s1[cr]);
                atomicAdd(&stats[CO + co0 + cr], (double)s2[cr]);
            }
        }
    }
}

// ---------------------------------------------------------------------------
__global__ void bnp_rD(const double* __restrict__ stats,
                       const float* __restrict__ g, const float* __restrict__ be,
                       float2* __restrict__ sc, int C, double invNL)
{
    int c = threadIdx.x;
    if (c >= C) return;
    double mu  = stats[c] * invNL;
    double var = stats[C + c] * invNL - mu * mu;
    double rs  = 1.0 / sqrt(var + 1e-5);
    double gv  = (double)g[c] * rs;
    double bv  = (double)be[c] - mu * gv;
    sc[c] = make_float2((float)gv, (float)bv);
}

// ---------------------------------------------------------------------------
// VQ stage 1: grid 1024 = 512 row-groups x 2 codebook halves. 64 rows/block,
// 4 lanes/row split over dims (16/lane in regs). Expanded form:
// argmin_j (ww_j - 2 z.w_j); ww partials precomputed into the stride-68 pad.
// ---------------------------------------------------------------------------
__global__ __launch_bounds__(256)
void vq1_rF(const float* __restrict__ z, const float* __restrict__ emb,
            float* __restrict__ d0, float* __restrict__ d1,
            int* __restrict__ j0, int* __restrict__ j1)
{
    __shared__ float ws[128 * 68];
    const int tid  = threadIdx.x;
    const int sub  = tid & 3;
    const int half = blockIdx.x & 1;
    const int r    = (blockIdx.x >> 1) * 64 + (tid >> 2);

    const float4* zp = (const float4*)(z + (size_t)r * 64 + sub * 16);
    float4 z0 = zp[0], z1 = zp[1], z2 = zp[2], z3 = zp[3];

    float zzp = 0.f;
    zzp = fmaf(z0.x,z0.x,zzp); zzp = fmaf(z0.y,z0.y,zzp);
    zzp = fmaf(z0.z,z0.z,zzp); zzp = fmaf(z0.w,z0.w,zzp);
    zzp = fmaf(z1.x,z1.x,zzp); zzp = fmaf(z1.y,z1.y,zzp);
    zzp = fmaf(z1.z,z1.z,zzp); zzp = fmaf(z1.w,z1.w,zzp);
    zzp = fmaf(z2.x,z2.x,zzp); zzp = fmaf(z2.y,z2.y,zzp);
    zzp = fmaf(z2.z,z2.z,zzp); zzp = fmaf(z2.w,z2.w,zzp);
    zzp = fmaf(z3.x,z3.x,zzp); zzp = fmaf(z3.y,z3.y,zzp);
    zzp = fmaf(z3.z,z3.z,zzp); zzp = fmaf(z3.w,z3.w,zzp);

    float best = 3.4e38f;
    int   bj   = 0;
    for (int cc = 0; cc < 2; ++cc) {
        const int c0 = half * 256 + cc * 128;
        __syncthreads();
        for (int i = tid; i < 128 * 16; i += 256) {
            int j = i >> 4, q = i & 15;
            ((float4*)ws)[j * 17 + q] = ((const float4*)(emb + c0 * 64))[i];
        }
        __syncthreads();
        for (int i = tid; i < 512; i += 256) {
            int j = i >> 2, s = i & 3;
            const float4* p = (const float4*)&ws[j * 68 + s * 16];
            float4 a = p[0], b = p[1], c = p[2], d = p[3];
            float ww = 0.f;
            ww = fmaf(a.x,a.x,ww); ww = fmaf(a.y,a.y,ww);
            ww = fmaf(a.z,a.z,ww); ww = fmaf(a.w,a.w,ww);
            ww = fmaf(b.x,b.x,ww); ww = fmaf(b.y,b.y,ww);
            ww = fmaf(b.z,b.z,ww); ww = fmaf(b.w,b.w,ww);
            ww = fmaf(c.x,c.x,ww); ww = fmaf(c.y,c.y,ww);
            ww = fmaf(c.z,c.z,ww); ww = fmaf(c.w,c.w,ww);
            ww = fmaf(d.x,d.x,ww); ww = fmaf(d.y,d.y,ww);
            ww = fmaf(d.z,d.z,ww); ww = fmaf(d.w,d.w,ww);
            ws[j * 68 + 64 + s] = ww;
        }
        __syncthreads();
        for (int j = 0; j < 128; ++j) {
            const float4* wp = (const float4*)&ws[j * 68 + sub * 16];
            float4 w0 = wp[0], w1 = wp[1], w2 = wp[2], w3 = wp[3];
            float dot = 0.f;
            dot = fmaf(z0.x,w0.x,dot); dot = fmaf(z0.y,w0.y,dot);
            dot = fmaf(z0.z,w0.z,dot); dot = fmaf(z0.w,w0.w,dot);
            dot = fmaf(z1.x,w1.x,dot); dot = fmaf(z1.y,w1.y,dot);
            dot = fmaf(z1.z,w1.z,dot); dot = fmaf(z1.w,w1.w,dot);
            dot = fmaf(z2.x,w2.x,dot); dot = fmaf(z2.y,w2.y,dot);
            dot = fmaf(z2.z,w2.z,dot); dot = fmaf(z2.w,w2.w,dot);
            dot = fmaf(z3.x,w3.x,dot); dot = fmaf(z3.y,w3.y,dot);
            dot = fmaf(z3.z,w3.z,dot); dot = fmaf(z3.w,w3.w,dot);
            float t = fmaf(dot, -2.f, ws[j * 68 + 64 + sub]);
            t += __shfl_xor(t, 1, 64);
            t += __shfl_xor(t, 2, 64);
            if (t < best) { best = t; bj = c0 + j; }
        }
    }

    float zz = zzp;
    zz += __shfl_xor(zz, 1, 64);
    zz += __shfl_xor(zz, 2, 64);

    if (sub == 0) {
        if (half) { d1[r] = zz + best; j1[r] = bj; }
        else      { d0[r] = zz + best; j0[r] = bj; }
    }
}

// VQ stage 2: combine halves, gather hq rows, accumulate loss.
__global__ __launch_bounds__(256)
void vq2_rF(const float* __restrict__ d0, const float* __restrict__ d1,
            const int* __restrict__ j0, const int* __restrict__ j1,
            const float* __restrict__ emb, float* __restrict__ hq,
            double* __restrict__ lossAcc)
{
    const int r = blockIdx.x * 256 + threadIdx.x;
    float da = d0[r], db = d1[r];
    bool pick1 = db < da;                    // ties -> half 0 (lower index)
    float d = pick1 ? db : da;
    int   j = pick1 ? j1[r] : j0[r];

    const float4* ep = (const float4*)(emb + (size_t)j * 64);
    float4* hp = (float4*)(hq + (size_t)r * 64);
#pragma unroll
    for (int t = 0; t < 16; ++t) hp[t] = ep[t];

    float s = d;
#pragma unroll
    for (int m = 1; m < 64; m <<= 1) s += __shfl_xor(s, m, 64);
    if ((threadIdx.x & 63) == 0) atomicAdd(lossAcc, (double)s);
}

__global__ void zd_rD(double* p, int n) {
    int i = blockIdx.x * 256 + threadIdx.x;
    if (i < n) p[i] = 0.0;
}

__global__ void wsguard_rD(float* p, int n) {
    int i = blockIdx.x * 256 + threadIdx.x;
    if (i < n) p[i] = 1000.0f;
}

__global__ void lossfin_rD(const double* acc, float* out) {
    float m = (float)(acc[0] * (1.0 / 32768.0));
    out[2097152] = m;   // commit_loss
    out[2097153] = m;   // vq_loss
}

extern "C" void kernel_launch(void* const* d_in, const int* in_sizes, int n_in,
                              void* d_out, int out_size, void* d_ws, size_t ws_size,
                              hipStream_t stream)
{
    const size_t NEED = (size_t)3 * 4194304 * 4 + 2305 * 8 + 1152 * 8 + 64;
    if (ws_size < NEED) {
        wsguard_rD<<<dim3((out_size + 255) / 256), 256, 0, stream>>>((float*)d_out, out_size);
        return;
    }

    const float* x        = (const float*)d_in[0];
    const float* w_conv   = (const float*)d_in[1];
    const float* b_conv   = (const float*)d_in[2];
    const float* g_conv   = (const float*)d_in[3];
    const float* be_conv  = (const float*)d_in[4];
    const float* w_r1     = (const float*)d_in[5];
    const float* b_r1     = (const float*)d_in[6];
    const float* g_r1     = (const float*)d_in[7];
    const float* be_r1    = (const float*)d_in[8];
    const float* w_ds1    = (const float*)d_in[9];
    const float* b_ds1    = (const float*)d_in[10];
    const float* w_r2     = (const float*)d_in[11];
    const float* b_r2     = (const float*)d_in[12];
    const float* g_r2     = (const float*)d_in[13];
    const float* be_r2    = (const float*)d_in[14];
    const float* w_1to2   = (const float*)d_in[15];
    const float* w_ds2    = (const float*)d_in[16];
    const float* b_ds2    = (const float*)d_in[17];
    const float* embed_w  = (const float*)d_in[18];
    const float* w_us2    = (const float*)d_in[19];
    const float* b_us2    = (const float*)d_in[20];
    const float* w_dr2    = (const float*)d_in[21];
    const float* b_dr2    = (const float*)d_in[22];
    const float* g_dr2    = (const float*)d_in[23];
    const float* be_dr2   = (const float*)d_in[24];
    const float* w_2to1   = (const float*)d_in[25];
    const float* w_us1    = (const float*)d_in[26];
    const float* b_us1    = (const float*)d_in[27];
    const float* w_dr1    = (const float*)d_in[28];
    const float* b_dr1    = (const float*)d_in[29];
    const float* g_dr1    = (const float*)d_in[30];
    const float* be_dr1   = (const float*)d_in[31];
    const float* w_deconv = (const float*)d_in[32];
    const float* b_deconv = (const float*)d_in[33];

    float* out = (float*)d_out;

    float*  B0 = (float*)d_ws;
    float*  B1 = B0 + 4194304;
    float*  B2 = B0 + 2 * 4194304;
    double* SD = (double*)(B0 + 3 * 4194304);
    double* lossAcc = SD + 9 * 256;
    float2* SC = (float2*)(SD + 2305);

    // VQ scratch lives in B0 (free between ds2 and us2)
    float* vqd0 = B0;
    float* vqd1 = B0 + 32768;
    int*   vqj0 = (int*)(B0 + 65536);
    int*   vqj1 = (int*)(B0 + 98304);

    const int N = 64;
    const double i64k = 1.0 / 65536.0;
    const double i32k = 1.0 / 32768.0;
    const float2* NOSC = nullptr;
    const float*  NOP  = nullptr;

    zd_rD<<<dim3(10), 256, 0, stream>>>(SD, 9 * 256 + 1);

    // ---- encoder ----
    conv_rM<32,64,7,0,128,32,4,3, F_BIAS|F_STATS>
        <<<dim3(8, N, 2), 256, 0, stream>>>(x, NOSC, NOP, NOSC, w_conv, b_conv,
            NOP, NOSC, SD+0*256, B0, 1024, 1024, 32, 32);
    bnp_rD<<<1, 128, 0, stream>>>(SD+0*256, g_conv, be_conv, SC+0*128, 64, i64k);

    conv_rM<64,64,3,0,64,32,4,1, F_BIAS|F_STATS|F_INBN>
        <<<dim3(16, N, 2), 256, 0, stream>>>(B0, SC+0*128, NOP, NOSC, w_r1, b_r1,
            NOP, NOSC, SD+1*256, B1, 1024, 1024, 64, 64);
    bnp_rD<<<1, 128, 0, stream>>>(SD+1*256, g_r1, be_r1, SC+1*128, 64, i64k);

    conv_rM<64,64,3,0,64,32,4,1, F_BIAS|F_STATS|F_INBN|F_INRELU>
        <<<dim3(16, N, 2), 256, 0, stream>>>(B1, SC+1*128, NOP, NOSC, w_r1+12288, b_r1+64,
            NOP, NOSC, SD+2*256, B2, 1024, 1024, 64, 64);
    bnp_rD<<<1, 128, 0, stream>>>(SD+2*256, g_r1+64, be_r1+64, SC+2*128, 64, i64k);

    conv_rM<64,64,3,0,64,32,4,1, F_BIAS|F_STATS|F_INBN|F_INRELU>
        <<<dim3(16, N, 2), 256, 0, stream>>>(B2, SC+2*128, NOP, NOSC, w_r1+24576, b_r1+128,
            NOP, NOSC, SD+3*256, B1, 1024, 1024, 64, 64);
    bnp_rD<<<1, 128, 0, stream>>>(SD+3*256, g_r1+128, be_r1+128, SC+3*128, 64, i64k);

    // ds1: input = bn3(B1) + bn0(B0) -> stride-2 conv -> B2
    conv_rM<64,64,2,1,64,32,4,0, F_BIAS|F_INBN|F_INB|F_INBBN>
        <<<dim3(8, N, 2), 256, 0, stream>>>(B1, SC+3*128, B0, SC+0*128, w_ds1, b_ds1,
            NOP, NOSC, nullptr, B2, 1024, 512, 64, 64);

    conv_rM<64,128,3,0,64,32,4,1, F_BIAS|F_STATS>
        <<<dim3(8, N, 4), 256, 0, stream>>>(B2, NOSC, NOP, NOSC, w_r2, b_r2,
            NOP, NOSC, SD+4*256, B1, 512, 512, 64, 64);
    bnp_rD<<<1, 128, 0, stream>>>(SD+4*256, g_r2, be_r2, SC+4*128, 128, i32k);

    // 1to2: conv(B2,w_1to2) + bn4(B1) -> B0   (w_1to2 is (O=128,I=64,K=1) -> wci=64)
    conv_rM<64,128,1,0,64,32,4,0, F_ADD|F_ADDBN>
        <<<dim3(8, N, 4), 256, 0, stream>>>(B2, NOSC, NOP, NOSC, w_1to2, NOP,
            B1, SC+4*128, nullptr, B0, 512, 512, 64, 64);

    // ds2: B0 -> stride-2 conv -> B1
    conv_rM<128,128,2,1,32,32,4,0, F_BIAS>
        <<<dim3(8, N, 4), 256, 0, stream>>>(B0, NOSC, NOP, NOSC, w_ds2, b_ds2,
            NOP, NOSC, nullptr, B1, 512, 256, 128, 128);

    // ---- vector quantization ----
    vq1_rF<<<dim3(1024), 256, 0, stream>>>(B1, embed_w, vqd0, vqd1, vqj0, vqj1);
    vq2_rF<<<dim3(128), 256, 0, stream>>>(vqd0, vqd1, vqj0, vqj1, embed_w, B2, lossAcc);
    lossfin_rD<<<1, 1, 0, stream>>>(lossAcc, out);

    // ---- decoder ----
    // us2: B2(hq) -> transposed stride-2 -> B0
    conv_rM<128,128,2,2,64,32,4,0, F_BIAS>
        <<<dim3(8, N, 4), 256, 0, stream>>>(B2, NOSC, NOP, NOSC, w_us2, b_us2,
            NOP, NOSC, nullptr, B0, 256, 512, 128, 128);

    // dr2 (CI=128 split 2x64): a = ci 0..63 + bias -> B1
    conv_rM<64,64,3,0,64,32,4,1, F_WT|F_BIAS>
        <<<dim3(8, N, 2), 256, 0, stream>>>(B0, NOSC, NOP, NOSC, w_dr2, b_dr2,
            NOP, NOSC, nullptr, B1, 512, 512, 128, 64);
    conv_rM<64,64,3,0,64,32,4,1, F_WT|F_STATS|F_ADD>
        <<<dim3(8, N, 2), 256, 0, stream>>>(B0 + (size_t)64*512, NOSC, NOP, NOSC,
            w_dr2 + 64*64*3, NOP, B1, NOSC, SD+5*256, B1, 512, 512, 128, 64);
    bnp_rD<<<1, 128, 0, stream>>>(SD+5*256, g_dr2, be_dr2, SC+5*128, 64, i32k);

    // 2to1 (CI=128 split): a = conv(ci 0..63) + bn5(B1) -> B2
    conv_rM<64,64,1,0,64,32,4,0, F_ADD|F_ADDBN>
        <<<dim3(8, N, 2), 256, 0, stream>>>(B0, NOSC, NOP, NOSC, w_2to1, NOP,
            B1, SC+5*128, nullptr, B2, 512, 512, 128, 128);
    conv_rM<64,64,1,0,64,32,4,0, F_ADD>
        <<<dim3(8, N, 2), 256, 0, stream>>>(B0 + (size_t)64*512, NOSC, NOP, NOSC,
            w_2to1 + 64, NOP, B2, NOSC, nullptr, B2, 512, 512, 128, 128);

    // us1: B2 -> transposed stride-2 -> B0 (t, kept raw for final skip)
    conv_rM<64,64,2,2,128,32,4,0, F_BIAS>
        <<<dim3(8, N, 2), 256, 0, stream>>>(B2, NOSC, NOP, NOSC, w_us1, b_us1,
            NOP, NOSC, nullptr, B0, 512, 1024, 64, 64);

    conv_rM<64,64,3,0,64,32,4,1, F_WT|F_BIAS|F_STATS>
        <<<dim3(16, N, 2), 256, 0, stream>>>(B0, NOSC, NOP, NOSC, w_dr1, b_dr1,
            NOP, NOSC, SD+6*256, B1, 1024, 1024, 64, 64);
    bnp_rD<<<1, 128, 0, stream>>>(SD+6*256, g_dr1, be_dr1, SC+6*128, 64, i64k);

    conv_rM<64,64,3,0,64,32,4,1, F_WT|F_BIAS|F_STATS|F_INBN|F_INRELU>
        <<<dim3(16, N, 2), 256, 0, stream>>>(B1, SC+6*128, NOP, NOSC, w_dr1+12288, b_dr1+64,
            NOP, NOSC, SD+7*256, B2, 1024, 1024, 64, 64);
    bnp_rD<<<1, 128, 0, stream>>>(SD+7*256, g_dr1+64, be_dr1+64, SC+7*128, 64, i64k);

    conv_rM<64,64,3,0,64,32,4,1, F_WT|F_BIAS|F_STATS|F_INBN|F_INRELU>
        <<<dim3(16, N, 2), 256, 0, stream>>>(B2, SC+7*128, NOP, NOSC, w_dr1+24576, b_dr1+128,
            NOP, NOSC, SD+8*256, B1, 1024, 1024, 64, 64);
    bnp_rD<<<1, 128, 0, stream>>>(SD+8*256, g_dr1+128, be_dr1+128, SC+8*128, 64, i64k);

    // deconv: input = bn8(B1) + B0 raw -> convT K=7 -> out
    conv_rM<64,32,7,0,128,16,4,3, F_WT|F_BIAS|F_INBN|F_INB>
        <<<dim3(8, N, 2), 256, 0, stream>>>(B1, SC+8*128, B0, NOSC, w_deconv, b_deconv,
            NOP, NOSC, nullptr, out, 1024, 1024, 64, 64);
}

// Round 11
// 1215.634 us; speedup vs baseline: 1.3479x; 1.3479x over previous
//
// ===========================================================================
// R24 — R19 geometry verbatim (best passing: 1215us; TL=128 confirmed optimal
// by R15/R23 tile sweep) + bnp fused into consumer convs: each block computes
// BN scale/shift from the double stats (identical math to bnp -> bit-identical
// outputs) in a preamble overlapped with phase-1 global-load latency.
// Removes 9 bnp dispatches. VQ = R15 dot-form split (unchanged).
// ===========================================================================
#include <hip/hip_runtime.h>
#include <stdint.h>

#define F_WT     1
#define F_STATS  2
#define F_BIAS   4
#define F_INBN   8
#define F_INRELU 16
#define F_INB    32
#define F_INBBN  64
#define F_ADD    128
#define F_ADDBN  256

// ---------------------------------------------------------------------------
// Tiled conv, CR outputs/thread in channel dim.
// MODE 0: stride-1 (PAD template), WT: ConvTranspose (I,O,K) flipped.
// MODE 1: stride-2 downsample K=2. MODE 2: stride-2 transposed upsample K=2.
// 256 thr = NCG(=COB/CR) co-groups x LT(=256/NCG) l-groups, TLT=TL/LT.
// BN scales computed per-block from double stats (fused bnp).
// ---------------------------------------------------------------------------
template<int CI, int CO, int K, int MODE, int TL, int COB, int CR, int PAD,
         int FLAGS>
__global__ __launch_bounds__(256)
void conv_rN(const float* __restrict__ xa,
             const double* __restrict__ sdA, const float* __restrict__ gA,
             const float* __restrict__ beA,
             const float* __restrict__ xb,
             const double* __restrict__ sdB, const float* __restrict__ gB,
             const float* __restrict__ beB,
             const float* __restrict__ w,  const float* __restrict__ bias,
             const float* __restrict__ addsrc,
             const double* __restrict__ sdAdd, const float* __restrict__ gAdd,
             const float* __restrict__ beAdd,
             double* __restrict__ stats, float* __restrict__ yout,
             int Lin, int Lout, int cis, int wci,
             double invA, double invB, double invAdd)
{
    constexpr int NCG  = COB / CR;          // co groups
    constexpr int LT   = 256 / NCG;         // l groups
    constexpr int TLT  = TL / LT;           // outputs per thread per co
    constexpr int SPAN = (MODE == 0) ? (TL + K - 1)
                       : (MODE == 1) ? ((TL - 1) * 2 + K)
                       : (TL / 2);
    constexpr int SPANP = (SPAN + 3) & ~3;
    constexpr int WR    = K * CR;
    constexpr int WRP   = (WR + 3) & ~3;
    constexpr int WROW  = CI * WRP + 4;     // +4 float stagger per cog
    constexpr int XR    = (MODE == 0) ? (TLT + K - 1)
                        : (MODE == 1) ? ((TLT - 1) * 2 + K)
                        : ((TLT + 1) / 2);
    // aligned-window shift: x0 = ltile*stride - PAD; ALN makes loads 16B-aligned
    constexpr int ALN  = (MODE == 0) ? ((4 - (PAD & 3)) & 3) : 0;
    constexpr int NW   = (SPAN + ALN + 3) / 4;     // f4 loads per row
    constexpr int NTASK = CI * NW;
    constexpr int PT    = (NTASK + 255) / 256;
    constexpr bool F4ST = (ALN == 0) && (SPAN % 4 == 0);
    constexpr int WNT   = NCG * CI * WR;
    constexpr int WPT   = (WNT + 255) / 256;

    __shared__ float xs[CI * SPANP];
    __shared__ float wl[NCG * WROW];
    __shared__ float2 sclA[(FLAGS & F_INBN)  ? CI : 1];
    __shared__ float2 sclB[(FLAGS & F_INBBN) ? CI : 1];
    __shared__ float2 sclD[(FLAGS & F_ADDBN) ? CO : 1];

    const int tid    = threadIdx.x;
    const int ltile  = blockIdx.x;
    const int n      = blockIdx.y;
    const int coBase = blockIdx.z * COB;

    // ---- weights -> LDS (two-phase batched) ----
    {
        float wvv[WPT];
#pragma unroll
        for (int p = 0; p < WPT; ++p) {
            int i = tid + p * 256;
            float v = 0.f;
            if (i < WNT) {
                int cogi = i / (CI * WR);
                int rem  = i - cogi * (CI * WR);
                int ci   = rem / WR;
                int rem2 = rem - ci * WR;
                int k    = rem2 / CR;
                int cr   = rem2 - k * CR;
                int co   = coBase + cogi * CR + cr;
                int src;
                if (FLAGS & F_WT)   src = (ci * CO + co) * K + (K - 1 - k);
                else if (MODE == 2) src = (ci * CO + co) * K + k;
                else                src = (co * wci + ci) * K + k;
                v = w[src];
            }
            wvv[p] = v;
        }
#pragma unroll
        for (int p = 0; p < WPT; ++p) {
            int i = tid + p * 256;
            if (i < WNT) {
                int cogi = i / (CI * WR);
                int rem  = i - cogi * (CI * WR);
                int ci   = rem / WR;
                int rem2 = rem - ci * WR;
                int k    = rem2 / CR;
                int cr   = rem2 - k * CR;
                wl[cogi * WROW + ci * WRP + k * CR + cr] = wvv[p];
            }
        }
    }

    // ---- x -> LDS, two-phase: batched f4 loads, then transform+write ----
    int x0;
    if (MODE == 0)      x0 = ltile * TL - PAD;
    else if (MODE == 1) x0 = ltile * TL * 2;
    else                x0 = ltile * (TL / 2);
    const int xw0 = x0 - ALN;               // aligned window start

    {
        float4 va[PT];
        float4 vb[PT];
#pragma unroll
        for (int p = 0; p < PT; ++p) {
            int i = tid + p * 256;
            float4 v = make_float4(0.f, 0.f, 0.f, 0.f);
            float4 u = make_float4(0.f, 0.f, 0.f, 0.f);
            if (i < NTASK) {
                int ci  = i / NW;
                int q   = i - ci * NW;
                int xl4 = xw0 + 4 * q;
                size_t rb = ((size_t)n * cis + ci) * (size_t)Lin;
                if (xl4 >= 0 && xl4 + 3 < Lin) {
                    v = *(const float4*)(xa + rb + xl4);
                    if (FLAGS & F_INB) u = *(const float4*)(xb + rb + xl4);
                } else {
                    float* pv = (float*)&v;
                    float* pu = (float*)&u;
#pragma unroll
                    for (int t = 0; t < 4; ++t) {
                        int xl = xl4 + t;
                        if (xl >= 0 && xl < Lin) {
                            pv[t] = xa[rb + xl];
                            if (FLAGS & F_INB) pu[t] = xb[rb + xl];
                        }
                    }
                }
            }
            va[p] = v;
            if (FLAGS & F_INB) vb[p] = u;
        }

        // ---- fused-bnp preamble (overlaps the global-load latency above):
        //      identical double math to the old bnp kernel -> bit-identical.
        if constexpr ((FLAGS & F_INBN) != 0) {
            for (int c = tid; c < CI; c += 256) {
                double mu  = sdA[c] * invA;
                double var = sdA[CI + c] * invA - mu * mu;
                double rs  = 1.0 / sqrt(var + 1e-5);
                double gv  = (double)gA[c] * rs;
                double bv  = (double)beA[c] - mu * gv;
                sclA[c] = make_float2((float)gv, (float)bv);
            }
        }
        if constexpr ((FLAGS & F_INBBN) != 0) {
            for (int c = tid; c < CI; c += 256) {
                double mu  = sdB[c] * invB;
                double var = sdB[CI + c] * invB - mu * mu;
                double rs  = 1.0 / sqrt(var + 1e-5);
                double gv  = (double)gB[c] * rs;
                double bv  = (double)beB[c] - mu * gv;
                sclB[c] = make_float2((float)gv, (float)bv);
            }
        }
        if constexpr ((FLAGS & F_ADDBN) != 0) {
            for (int c = tid; c < CO; c += 256) {
                double mu  = sdAdd[c] * invAdd;
                double var = sdAdd[CO + c] * invAdd - mu * mu;
                double rs  = 1.0 / sqrt(var + 1e-5);
                double gv  = (double)gAdd[c] * rs;
                double bv  = (double)beAdd[c] - mu * gv;
                sclD[c] = make_float2((float)gv, (float)bv);
            }
        }
        if constexpr ((FLAGS & (F_INBN | F_INBBN | F_ADDBN)) != 0)
            __syncthreads();    // scl* visible before transform phase

#pragma unroll
        for (int p = 0; p < PT; ++p) {
            int i = tid + p * 256;
            if (i < NTASK) {
                int ci = i / NW;
                int q  = i - ci * NW;
                int xl4 = xw0 + 4 * q;
                float4 v = va[p];
                float* pv = (float*)&v;
                if (FLAGS & F_INBN) {
                    float2 t = sclA[ci];
#pragma unroll
                    for (int e = 0; e < 4; ++e) pv[e] = pv[e] * t.x + t.y;
                }
                if (FLAGS & F_INRELU) {
#pragma unroll
                    for (int e = 0; e < 4; ++e) pv[e] = fmaxf(pv[e], 0.f);
                }
                if (FLAGS & F_INB) {
                    float4 u = vb[p];
                    float* pu = (float*)&u;
                    if (FLAGS & F_INBBN) {
                        float2 t = sclB[ci];
#pragma unroll
                        for (int e = 0; e < 4; ++e) {
                            float uu = pu[e] * t.x + t.y;
                            pv[e] += uu;
                        }
                    } else {
#pragma unroll
                        for (int e = 0; e < 4; ++e) pv[e] += pu[e];
                    }
                }
                // zero-padding: transforms must NOT touch OOB slots.
#pragma unroll
                for (int e = 0; e < 4; ++e) {
                    int xl = xl4 + e;
                    if (xl < 0 || xl >= Lin) pv[e] = 0.f;
                }
                if constexpr (F4ST) {
                    *(float4*)&xs[ci * SPANP + 4 * q] = v;
                } else {
#pragma unroll
                    for (int t = 0; t < 4; ++t) {
                        int s = 4 * q + t - ALN;
                        if (s >= 0 && s < SPAN) xs[ci * SPANP + s] = pv[t];
                    }
                }
            }
        }
    }
    __syncthreads();

    const int cog   = tid / LT;
    const int lg    = tid % LT;
    const int co0   = coBase + cog * CR;
    const int loOff = lg * TLT;
    const int xoff  = (MODE == 1) ? loOff * 2
                    : (MODE == 2) ? (loOff >> 1) : loOff;

    float acc[CR][TLT];
#pragma unroll
    for (int cr = 0; cr < CR; ++cr) {
        float b = (FLAGS & F_BIAS) ? bias[co0 + cr] : 0.f;
#pragma unroll
        for (int j = 0; j < TLT; ++j) acc[cr][j] = b;
    }

    float xA[XR], xB[XR], wA[WR], wB[WR];

    auto ldx = [&](float* dst, int c) {
        const int base = c * SPANP + xoff;
#pragma unroll
        for (int g = 0; g < XR; g += 4) {
            const float* p = &xs[base + g];
#pragma unroll
            for (int t = 0; t < 4; ++t)
                if (g + t < XR) dst[g + t] = p[t];
        }
    };
    auto ldw = [&](float* dst, int c) {
        const float* q = &wl[cog * WROW + c * WRP];
#pragma unroll
        for (int t = 0; t < WR; ++t) dst[t] = q[t];
    };
    auto dofma = [&](const float* xv, const float* wv) {
        if (MODE == 2) {
#pragma unroll
            for (int j = 0; j < TLT; ++j)
#pragma unroll
                for (int cr = 0; cr < CR; ++cr)
                    acc[cr][j] += wv[(j & 1) * CR + cr] * xv[j >> 1];
        } else {
#pragma unroll
            for (int k = 0; k < K; ++k)
#pragma unroll
                for (int j = 0; j < TLT; ++j)
#pragma unroll
                    for (int cr = 0; cr < CR; ++cr)
                        acc[cr][j] += wv[k * CR + cr]
                                    * xv[((MODE == 1) ? 2 * j : j) + k];
        }
    };

    if constexpr (K <= 3) {
        // register-double-buffered ci loop (CI even, >= 32)
        ldx(xA, 0); ldw(wA, 0);
        for (int ci = 0; ci + 2 < CI; ci += 2) {
            ldx(xB, ci + 1); ldw(wB, ci + 1);
            dofma(xA, wA);
            ldx(xA, ci + 2); ldw(wA, ci + 2);
            dofma(xB, wB);
        }
        ldx(xB, CI - 1); ldw(wB, CI - 1);
        dofma(xA, wA);
        dofma(xB, wB);
    } else {
#pragma unroll 2
        for (int ci = 0; ci < CI; ++ci) {
            ldx(xA, ci); ldw(wA, ci);
            dofma(xA, wA);
        }
    }

    // ---- epilogue: output-side add (opt BN), store, stats ----
    const int lo0 = ltile * TL + loOff;
#pragma unroll
    for (int cr = 0; cr < CR; ++cr) {
        size_t ob = ((size_t)n * CO + (co0 + cr)) * (size_t)Lout + lo0;
        if (FLAGS & F_ADD) {
            float2 t = (FLAGS & F_ADDBN) ? sclD[co0 + cr] : make_float2(1.f, 0.f);
            if constexpr (TLT % 4 == 0) {
#pragma unroll
                for (int jv = 0; jv < TLT / 4; ++jv) {
                    float4 av = ((const float4*)(addsrc + ob))[jv];
                    float* a4 = &acc[cr][jv * 4];
                    if (FLAGS & F_ADDBN) {
                        a4[0] += av.x * t.x + t.y; a4[1] += av.y * t.x + t.y;
                        a4[2] += av.z * t.x + t.y; a4[3] += av.w * t.x + t.y;
                    } else {
                        a4[0] += av.x; a4[1] += av.y; a4[2] += av.z; a4[3] += av.w;
                    }
                }
            } else {
#pragma unroll
                for (int j = 0; j < TLT; ++j) {
                    float a = addsrc[ob + j];
                    acc[cr][j] += (FLAGS & F_ADDBN) ? (a * t.x + t.y) : a;
                }
            }
        }
        if constexpr (TLT % 4 == 0) {
#pragma unroll
            for (int jv = 0; jv < TLT / 4; ++jv) {
                float4 sv = make_float4(acc[cr][jv*4+0], acc[cr][jv*4+1],
                                        acc[cr][jv*4+2], acc[cr][jv*4+3]);
                ((float4*)(yout + ob))[jv] = sv;
            }
        } else {
#pragma unroll
            for (int j = 0; j < TLT; ++j) yout[ob + j] = acc[cr][j];
        }
    }

    if (FLAGS & F_STATS) {
        float s1[CR], s2[CR];
#pragma unroll
        for (int cr = 0; cr < CR; ++cr) {
            s1[cr] = 0.f; s2[cr] = 0.f;
#pragma unroll
            for (int j = 0; j < TLT; ++j) {
                s1[cr] += acc[cr][j];
                s2[cr] += acc[cr][j] * acc[cr][j];
            }
        }
#pragma unroll
        for (int m = 1; m < LT; m <<= 1) {
#pragma unroll
            for (int cr = 0; cr < CR; ++cr) {
                s1[cr] += __shfl_xor(s1[cr], m, 64);
                s2[cr] += __shfl_xor(s2[cr], m, 64);
            }
        }
        if ((tid & (LT - 1)) == 0) {
#pragma unroll
            for (int cr = 0; cr < CR; ++cr) {
                atomicAdd(&stats[co0 + cr],      (double)s1[cr]);
                atomicAdd(&stats[CO + co0 + cr], (double)s2[cr]);
            }
        }
    }
}

// ---------------------------------------------------------------------------
// VQ stage 1: grid 1024 = 512 row-groups x 2 codebook halves. 64 rows/block,
// 4 lanes/row split over dims (16/lane in regs). Expanded form:
// argmin_j (ww_j - 2 z.w_j); ww partials precomputed into the stride-68 pad.
// ---------------------------------------------------------------------------
__global__ __launch_bounds__(256)
void vq1_rF(const float* __restrict__ z, const float* __restrict__ emb,
            float* __restrict__ d0, float* __restrict__ d1,
            int* __restrict__ j0, int* __restrict__ j1)
{
    __shared__ float ws[128 * 68];
    const int tid  = threadIdx.x;
    const int sub  = tid & 3;
    const int half = blockIdx.x & 1;
    const int r    = (blockIdx.x >> 1) * 64 + (tid >> 2);

    const float4* zp = (const float4*)(z + (size_t)r * 64 + sub * 16);
    float4 z0 = zp[0], z1 = zp[1], z2 = zp[2], z3 = zp[3];

    float zzp = 0.f;
    zzp = fmaf(z0.x,z0.x,zzp); zzp = fmaf(z0.y,z0.y,zzp);
    zzp = fmaf(z0.z,z0.z,zzp); zzp = fmaf(z0.w,z0.w,zzp);
    zzp = fmaf(z1.x,z1.x,zzp); zzp = fmaf(z1.y,z1.y,zzp);
    zzp = fmaf(z1.z,z1.z,zzp); zzp = fmaf(z1.w,z1.w,zzp);
    zzp = fmaf(z2.x,z2.x,zzp); zzp = fmaf(z2.y,z2.y,zzp);
    zzp = fmaf(z2.z,z2.z,zzp); zzp = fmaf(z2.w,z2.w,zzp);
    zzp = fmaf(z3.x,z3.x,zzp); zzp = fmaf(z3.y,z3.y,zzp);
    zzp = fmaf(z3.z,z3.z,zzp); zzp = fmaf(z3.w,z3.w,zzp);

    float best = 3.4e38f;
    int   bj   = 0;
    for (int cc = 0; cc < 2; ++cc) {
        const int c0 = half * 256 + cc * 128;
        __syncthreads();
        for (int i = tid; i < 128 * 16; i += 256) {
            int j = i >> 4, q = i & 15;
            ((float4*)ws)[j * 17 + q] = ((const float4*)(emb + c0 * 64))[i];
        }
        __syncthreads();
        for (int i = tid; i < 512; i += 256) {
            int j = i >> 2, s = i & 3;
            const float4* p = (const float4*)&ws[j * 68 + s * 16];
            float4 a = p[0], b = p[1], c = p[2], d = p[3];
            float ww = 0.f;
            ww = fmaf(a.x,a.x,ww); ww = fmaf(a.y,a.y,ww);
            ww = fmaf(a.z,a.z,ww); ww = fmaf(a.w,a.w,ww);
            ww = fmaf(b.x,b.x,ww); ww = fmaf(b.y,b.y,ww);
            ww = fmaf(b.z,b.z,ww); ww = fmaf(b.w,b.w,ww);
            ww = fmaf(c.x,c.x,ww); ww = fmaf(c.y,c.y,ww);
            ww = fmaf(c.z,c.z,ww); ww = fmaf(c.w,c.w,ww);
            ww = fmaf(d.x,d.x,ww); ww = fmaf(d.y,d.y,ww);
            ww = fmaf(d.z,d.z,ww); ww = fmaf(d.w,d.w,ww);
            ws[j * 68 + 64 + s] = ww;
        }
        __syncthreads();
        for (int j = 0; j < 128; ++j) {
            const float4* wp = (const float4*)&ws[j * 68 + sub * 16];
            float4 w0 = wp[0], w1 = wp[1], w2 = wp[2], w3 = wp[3];
            float dot = 0.f;
            dot = fmaf(z0.x,w0.x,dot); dot = fmaf(z0.y,w0.y,dot);
            dot = fmaf(z0.z,w0.z,dot); dot = fmaf(z0.w,w0.w,dot);
            dot = fmaf(z1.x,w1.x,dot); dot = fmaf(z1.y,w1.y,dot);
            dot = fmaf(z1.z,w1.z,dot); dot = fmaf(z1.w,w1.w,dot);
            dot = fmaf(z2.x,w2.x,dot); dot = fmaf(z2.y,w2.y,dot);
            dot = fmaf(z2.z,w2.z,dot); dot = fmaf(z2.w,w2.w,dot);
            dot = fmaf(z3.x,w3.x,dot); dot = fmaf(z3.y,w3.y,dot);
            dot = fmaf(z3.z,w3.z,dot); dot = fmaf(z3.w,w3.w,dot);
            float t = fmaf(dot, -2.f, ws[j * 68 + 64 + sub]);
            t += __shfl_xor(t, 1, 64);
            t += __shfl_xor(t, 2, 64);
            if (t < best) { best = t; bj = c0 + j; }
        }
    }

    float zz = zzp;
    zz += __shfl_xor(zz, 1, 64);
    zz += __shfl_xor(zz, 2, 64);

    if (sub == 0) {
        if (half) { d1[r] = zz + best; j1[r] = bj; }
        else      { d0[r] = zz + best; j0[r] = bj; }
    }
}

// VQ stage 2: combine halves, gather hq rows, accumulate loss.
__global__ __launch_bounds__(256)
void vq2_rF(const float* __restrict__ d0, const float* __restrict__ d1,
            const int* __restrict__ j0, const int* __restrict__ j1,
            const float* __restrict__ emb, float* __restrict__ hq,
            double* __restrict__ lossAcc)
{
    const int r = blockIdx.x * 256 + threadIdx.x;
    float da = d0[r], db = d1[r];
    bool pick1 = db < da;                    // ties -> half 0 (lower index)
    float d = pick1 ? db : da;
    int   j = pick1 ? j1[r] : j0[r];

    const float4* ep = (const float4*)(emb + (size_t)j * 64);
    float4* hp = (float4*)(hq + (size_t)r * 64);
#pragma unroll
    for (int t = 0; t < 16; ++t) hp[t] = ep[t];

    float s = d;
#pragma unroll
    for (int m = 1; m < 64; m <<= 1) s += __shfl_xor(s, m, 64);
    if ((threadIdx.x & 63) == 0) atomicAdd(lossAcc, (double)s);
}

__global__ void zd_rD(double* p, int n) {
    int i = blockIdx.x * 256 + threadIdx.x;
    if (i < n) p[i] = 0.0;
}

__global__ void wsguard_rD(float* p, int n) {
    int i = blockIdx.x * 256 + threadIdx.x;
    if (i < n) p[i] = 1000.0f;
}

__global__ void lossfin_rD(const double* acc, float* out) {
    float m = (float)(acc[0] * (1.0 / 32768.0));
    out[2097152] = m;   // commit_loss
    out[2097153] = m;   // vq_loss
}

extern "C" void kernel_launch(void* const* d_in, const int* in_sizes, int n_in,
                              void* d_out, int out_size, void* d_ws, size_t ws_size,
                              hipStream_t stream)
{
    const size_t NEED = (size_t)3 * 4194304 * 4 + 2305 * 8 + 1152 * 8 + 64;
    if (ws_size < NEED) {
        wsguard_rD<<<dim3((out_size + 255) / 256), 256, 0, stream>>>((float*)d_out, out_size);
        return;
    }

    const float* x        = (const float*)d_in[0];
    const float* w_conv   = (const float*)d_in[1];
    const float* b_conv   = (const float*)d_in[2];
    const float* g_conv   = (const float*)d_in[3];
    const float* be_conv  = (const float*)d_in[4];
    const float* w_r1     = (const float*)d_in[5];
    const float* b_r1     = (const float*)d_in[6];
    const float* g_r1     = (const float*)d_in[7];
    const float* be_r1    = (const float*)d_in[8];
    const float* w_ds1    = (const float*)d_in[9];
    const float* b_ds1    = (const float*)d_in[10];
    const float* w_r2     = (const float*)d_in[11];
    const float* b_r2     = (const float*)d_in[12];
    const float* g_r2     = (const float*)d_in[13];
    const float* be_r2    = (const float*)d_in[14];
    const float* w_1to2   = (const float*)d_in[15];
    const float* w_ds2    = (const float*)d_in[16];
    const float* b_ds2    = (const float*)d_in[17];
    const float* embed_w  = (const float*)d_in[18];
    const float* w_us2    = (const float*)d_in[19];
    const float* b_us2    = (const float*)d_in[20];
    const float* w_dr2    = (const float*)d_in[21];
    const float* b_dr2    = (const float*)d_in[22];
    const float* g_dr2    = (const float*)d_in[23];
    const float* be_dr2   = (const float*)d_in[24];
    const float* w_2to1   = (const float*)d_in[25];
    const float* w_us1    = (const float*)d_in[26];
    const float* b_us1    = (const float*)d_in[27];
    const float* w_dr1    = (const float*)d_in[28];
    const float* b_dr1    = (const float*)d_in[29];
    const float* g_dr1    = (const float*)d_in[30];
    const float* be_dr1   = (const float*)d_in[31];
    const float* w_deconv = (const float*)d_in[32];
    const float* b_deconv = (const float*)d_in[33];

    float* out = (float*)d_out;

    float*  B0 = (float*)d_ws;
    float*  B1 = B0 + 4194304;
    float*  B2 = B0 + 2 * 4194304;
    double* SD = (double*)(B0 + 3 * 4194304);
    double* lossAcc = SD + 9 * 256;

    // VQ scratch lives in B0 (free between ds2 and us2)
    float* vqd0 = B0;
    float* vqd1 = B0 + 32768;
    int*   vqj0 = (int*)(B0 + 65536);
    int*   vqj1 = (int*)(B0 + 98304);

    const int N = 64;
    const double i64k = 1.0 / 65536.0;
    const double i32k = 1.0 / 32768.0;
    const float*  NOF = nullptr;
    const double* NOD = nullptr;

    zd_rD<<<dim3(10), 256, 0, stream>>>(SD, 9 * 256 + 1);

    // ---- encoder ----
    conv_rN<32,64,7,0,128,32,4,3, F_BIAS|F_STATS>
        <<<dim3(8, N, 2), 256, 0, stream>>>(x, NOD, NOF, NOF, NOF, NOD, NOF, NOF,
            w_conv, b_conv, NOF, NOD, NOF, NOF, SD+0*256, B0,
            1024, 1024, 32, 32, 0.0, 0.0, 0.0);

    conv_rN<64,64,3,0,128,32,4,1, F_BIAS|F_STATS|F_INBN>
        <<<dim3(8, N, 2), 256, 0, stream>>>(B0, SD+0*256, g_conv, be_conv,
            NOF, NOD, NOF, NOF, w_r1, b_r1, NOF, NOD, NOF, NOF, SD+1*256, B1,
            1024, 1024, 64, 64, i64k, 0.0, 0.0);

    conv_rN<64,64,3,0,128,32,4,1, F_BIAS|F_STATS|F_INBN|F_INRELU>
        <<<dim3(8, N, 2), 256, 0, stream>>>(B1, SD+1*256, g_r1, be_r1,
            NOF, NOD, NOF, NOF, w_r1+12288, b_r1+64, NOF, NOD, NOF, NOF, SD+2*256, B2,
            1024, 1024, 64, 64, i64k, 0.0, 0.0);

    conv_rN<64,64,3,0,128,32,4,1, F_BIAS|F_STATS|F_INBN|F_INRELU>
        <<<dim3(8, N, 2), 256, 0, stream>>>(B2, SD+2*256, g_r1+64, be_r1+64,
            NOF, NOD, NOF, NOF, w_r1+24576, b_r1+128, NOF, NOD, NOF, NOF, SD+3*256, B1,
            1024, 1024, 64, 64, i64k, 0.0, 0.0);

    // ds1: input = bn3(B1) + bn0(B0) -> stride-2 conv -> B2
    conv_rN<64,64,2,1,64,32,4,0, F_BIAS|F_INBN|F_INB|F_INBBN>
        <<<dim3(8, N, 2), 256, 0, stream>>>(B1, SD+3*256, g_r1+128, be_r1+128,
            B0, SD+0*256, g_conv, be_conv, w_ds1, b_ds1, NOF, NOD, NOF, NOF,
            nullptr, B2, 1024, 512, 64, 64, i64k, i64k, 0.0);

    conv_rN<64,128,3,0,128,32,4,1, F_BIAS|F_STATS>
        <<<dim3(4, N, 4), 256, 0, stream>>>(B2, NOD, NOF, NOF, NOF, NOD, NOF, NOF,
            w_r2, b_r2, NOF, NOD, NOF, NOF, SD+4*256, B1,
            512, 512, 64, 64, 0.0, 0.0, 0.0);

    // 1to2: conv(B2,w_1to2) + bn4(B1) -> B0  (w_1to2 is (O=128,I=64,K=1) -> wci=64)
    conv_rN<64,128,1,0,128,32,4,0, F_ADD|F_ADDBN>
        <<<dim3(4, N, 4), 256, 0, stream>>>(B2, NOD, NOF, NOF, NOF, NOD, NOF, NOF,
            w_1to2, NOF, B1, SD+4*256, g_r2, be_r2, nullptr, B0,
            512, 512, 64, 64, 0.0, 0.0, i32k);

    // ds2: B0 -> stride-2 conv -> B1
    conv_rN<128,128,2,1,32,32,4,0, F_BIAS>
        <<<dim3(8, N, 4), 256, 0, stream>>>(B0, NOD, NOF, NOF, NOF, NOD, NOF, NOF,
            w_ds2, b_ds2, NOF, NOD, NOF, NOF, nullptr, B1,
            512, 256, 128, 128, 0.0, 0.0, 0.0);

    // ---- vector quantization ----
    vq1_rF<<<dim3(1024), 256, 0, stream>>>(B1, embed_w, vqd0, vqd1, vqj0, vqj1);
    vq2_rF<<<dim3(128), 256, 0, stream>>>(vqd0, vqd1, vqj0, vqj1, embed_w, B2, lossAcc);
    lossfin_rD<<<1, 1, 0, stream>>>(lossAcc, out);

    // ---- decoder ----
    // us2: B2(hq) -> transposed stride-2 -> B0
    conv_rN<128,128,2,2,128,32,4,0, F_BIAS>
        <<<dim3(4, N, 4), 256, 0, stream>>>(B2, NOD, NOF, NOF, NOF, NOD, NOF, NOF,
            w_us2, b_us2, NOF, NOD, NOF, NOF, nullptr, B0,
            256, 512, 128, 128, 0.0, 0.0, 0.0);

    // dr2 (CI=128 split 2x64): a = ci 0..63 + bias -> B1
    conv_rN<64,64,3,0,128,32,4,1, F_WT|F_BIAS>
        <<<dim3(4, N, 2), 256, 0, stream>>>(B0, NOD, NOF, NOF, NOF, NOD, NOF, NOF,
            w_dr2, b_dr2, NOF, NOD, NOF, NOF, nullptr, B1,
            512, 512, 128, 64, 0.0, 0.0, 0.0);
    conv_rN<64,64,3,0,128,32,4,1, F_WT|F_STATS|F_ADD>
        <<<dim3(4, N, 2), 256, 0, stream>>>(B0 + (size_t)64*512, NOD, NOF, NOF,
            NOF, NOD, NOF, NOF, w_dr2 + 64*64*3, NOF, B1, NOD, NOF, NOF,
            SD+5*256, B1, 512, 512, 128, 64, 0.0, 0.0, 0.0);

    // 2to1 (CI=128 split): a = conv(ci 0..63) + bn5(B1) -> B2
    conv_rN<64,64,1,0,128,32,4,0, F_ADD|F_ADDBN>
        <<<dim3(4, N, 2), 256, 0, stream>>>(B0, NOD, NOF, NOF, NOF, NOD, NOF, NOF,
            w_2to1, NOF, B1, SD+5*256, g_dr2, be_dr2, nullptr, B2,
            512, 512, 128, 128, 0.0, 0.0, i32k);
    conv_rN<64,64,1,0,128,32,4,0, F_ADD>
        <<<dim3(4, N, 2), 256, 0, stream>>>(B0 + (size_t)64*512, NOD, NOF, NOF,
            NOF, NOD, NOF, NOF, w_2to1 + 64, NOF, B2, NOD, NOF, NOF,
            nullptr, B2, 512, 512, 128, 128, 0.0, 0.0, 0.0);

    // us1: B2 -> transposed stride-2 -> B0 (t, kept raw for final skip)
    conv_rN<64,64,2,2,128,32,4,0, F_BIAS>
        <<<dim3(8, N, 2), 256, 0, stream>>>(B2, NOD, NOF, NOF, NOF, NOD, NOF, NOF,
            w_us1, b_us1, NOF, NOD, NOF, NOF, nullptr, B0,
            512, 1024, 64, 64, 0.0, 0.0, 0.0);

    conv_rN<64,64,3,0,128,32,4,1, F_WT|F_BIAS|F_STATS>
        <<<dim3(8, N, 2), 256, 0, stream>>>(B0, NOD, NOF, NOF, NOF, NOD, NOF, NOF,
            w_dr1, b_dr1, NOF, NOD, NOF, NOF, SD+6*256, B1,
            1024, 1024, 64, 64, 0.0, 0.0, 0.0);

    conv_rN<64,64,3,0,128,32,4,1, F_WT|F_BIAS|F_STATS|F_INBN|F_INRELU>
        <<<dim3(8, N, 2), 256, 0, stream>>>(B1, SD+6*256, g_dr1, be_dr1,
            NOF, NOD, NOF, NOF, w_dr1+12288, b_dr1+64, NOF, NOD, NOF, NOF,
            SD+7*256, B2, 1024, 1024, 64, 64, i64k, 0.0, 0.0);

    conv_rN<64,64,3,0,128,32,4,1, F_WT|F_BIAS|F_STATS|F_INBN|F_INRELU>
        <<<dim3(8, N, 2), 256, 0, stream>>>(B2, SD+7*256, g_dr1+64, be_dr1+64,
            NOF, NOD, NOF, NOF, w_dr1+24576, b_dr1+128, NOF, NOD, NOF, NOF,
            SD+8*256, B1, 1024, 1024, 64, 64, i64k, 0.0, 0.0);

    // deconv: input = bn8(B1) + B0 raw -> convT K=7 -> out
    conv_rN<64,32,7,0,128,16,4,3, F_WT|F_BIAS|F_INBN|F_INB>
        <<<dim3(8, N, 2), 256, 0, stream>>>(B1, SD+8*256, g_dr1+128, be_dr1+128,
            B0, NOD, NOF, NOF, w_deconv, b_deconv, NOF, NOD, NOF, NOF,
            nullptr, out, 1024, 1024, 64, 64, i64k, 0.0, 0.0);
}

// Round 12
// 1008.709 us; speedup vs baseline: 1.6245x; 1.2051x over previous
//
// ===========================================================================
// R25 — R24 (1215us, replay-safe, fused bnp) + NT-tile loop: blocks process
// NT consecutive L-tiles, staging WEIGHTS ONCE (they're tile-invariant).
// 1024-block convs -> NT=2 -> 512 blocks = exactly 2/CU full residency,
// weight staging halved. 512-block convs keep NT=1 (don't starve CUs).
// Per-output ci/k order and expressions unchanged -> bit-identical outputs.
// VQ = R15 dot-form split (unchanged).
// ===========================================================================
#include <hip/hip_runtime.h>
#include <stdint.h>

#define F_WT     1
#define F_STATS  2
#define F_BIAS   4
#define F_INBN   8
#define F_INRELU 16
#define F_INB    32
#define F_INBBN  64
#define F_ADD    128
#define F_ADDBN  256

// ---------------------------------------------------------------------------
// Tiled conv, CR outputs/thread in channel dim, NT tiles per block.
// MODE 0: stride-1 (PAD template), WT: ConvTranspose (I,O,K) flipped.
// MODE 1: stride-2 downsample K=2. MODE 2: stride-2 transposed upsample K=2.
// 256 thr = NCG(=COB/CR) co-groups x LT(=256/NCG) l-groups, TLT=TL/LT.
// BN scales computed per-block from double stats (fused bnp).
// ---------------------------------------------------------------------------
template<int CI, int CO, int K, int MODE, int TL, int COB, int CR, int PAD,
         int NT, int FLAGS>
__global__ __launch_bounds__(256)
void conv_rO(const float* __restrict__ xa,
             const double* __restrict__ sdA, const float* __restrict__ gA,
             const float* __restrict__ beA,
             const float* __restrict__ xb,
             const double* __restrict__ sdB, const float* __restrict__ gB,
             const float* __restrict__ beB,
             const float* __restrict__ w,  const float* __restrict__ bias,
             const float* __restrict__ addsrc,
             const double* __restrict__ sdAdd, const float* __restrict__ gAdd,
             const float* __restrict__ beAdd,
             double* __restrict__ stats, float* __restrict__ yout,
             int Lin, int Lout, int cis, int wci,
             double invA, double invB, double invAdd)
{
    constexpr int NCG  = COB / CR;          // co groups
    constexpr int LT   = 256 / NCG;         // l groups
    constexpr int TLT  = TL / LT;           // outputs per thread per co
    constexpr int SPAN = (MODE == 0) ? (TL + K - 1)
                       : (MODE == 1) ? ((TL - 1) * 2 + K)
                       : (TL / 2);
    constexpr int SPANP = (SPAN + 3) & ~3;
    constexpr int WR    = K * CR;
    constexpr int WRP   = (WR + 3) & ~3;
    constexpr int WROW  = CI * WRP + 4;     // +4 float stagger per cog
    constexpr int XR    = (MODE == 0) ? (TLT + K - 1)
                        : (MODE == 1) ? ((TLT - 1) * 2 + K)
                        : ((TLT + 1) / 2);
    // aligned-window shift: x0 = ltile*stride - PAD; ALN makes loads 16B-aligned
    constexpr int ALN  = (MODE == 0) ? ((4 - (PAD & 3)) & 3) : 0;
    constexpr int NW   = (SPAN + ALN + 3) / 4;     // f4 loads per row
    constexpr int NTASK = CI * NW;
    constexpr int PT    = (NTASK + 255) / 256;
    constexpr bool F4ST = (ALN == 0) && (SPAN % 4 == 0);
    constexpr int WNT   = NCG * CI * WR;
    constexpr int WPT   = (WNT + 255) / 256;

    __shared__ float xs[CI * SPANP];
    __shared__ float wl[NCG * WROW];
    __shared__ float2 sclA[(FLAGS & F_INBN)  ? CI : 1];
    __shared__ float2 sclB[(FLAGS & F_INBBN) ? CI : 1];
    __shared__ float2 sclD[(FLAGS & F_ADDBN) ? CO : 1];

    const int tid    = threadIdx.x;
    const int n      = blockIdx.y;
    const int coBase = blockIdx.z * COB;

    // ---- weights -> LDS (once per block; tile-invariant) ----
    {
        float wvv[WPT];
#pragma unroll
        for (int p = 0; p < WPT; ++p) {
            int i = tid + p * 256;
            float v = 0.f;
            if (i < WNT) {
                int cogi = i / (CI * WR);
                int rem  = i - cogi * (CI * WR);
                int ci   = rem / WR;
                int rem2 = rem - ci * WR;
                int k    = rem2 / CR;
                int cr   = rem2 - k * CR;
                int co   = coBase + cogi * CR + cr;
                int src;
                if (FLAGS & F_WT)   src = (ci * CO + co) * K + (K - 1 - k);
                else if (MODE == 2) src = (ci * CO + co) * K + k;
                else                src = (co * wci + ci) * K + k;
                v = w[src];
            }
            wvv[p] = v;
        }
#pragma unroll
        for (int p = 0; p < WPT; ++p) {
            int i = tid + p * 256;
            if (i < WNT) {
                int cogi = i / (CI * WR);
                int rem  = i - cogi * (CI * WR);
                int ci   = rem / WR;
                int rem2 = rem - ci * WR;
                int k    = rem2 / CR;
                int cr   = rem2 - k * CR;
                wl[cogi * WROW + ci * WRP + k * CR + cr] = wvv[p];
            }
        }
    }

    const int cog   = tid / LT;
    const int lg    = tid % LT;
    const int co0   = coBase + cog * CR;
    const int loOff = lg * TLT;
    const int xoff  = (MODE == 1) ? loOff * 2
                    : (MODE == 2) ? (loOff >> 1) : loOff;

    for (int tt = 0; tt < NT; ++tt) {
        const int ltile = blockIdx.x * NT + tt;
        if (tt > 0) __syncthreads();      // prior tile's xs reads complete

        int x0;
        if (MODE == 0)      x0 = ltile * TL - PAD;
        else if (MODE == 1) x0 = ltile * TL * 2;
        else                x0 = ltile * (TL / 2);
        const int xw0 = x0 - ALN;         // aligned window start

        {
            float4 va[PT];
            float4 vb[PT];
#pragma unroll
            for (int p = 0; p < PT; ++p) {
                int i = tid + p * 256;
                float4 v = make_float4(0.f, 0.f, 0.f, 0.f);
                float4 u = make_float4(0.f, 0.f, 0.f, 0.f);
                if (i < NTASK) {
                    int ci  = i / NW;
                    int q   = i - ci * NW;
                    int xl4 = xw0 + 4 * q;
                    size_t rb = ((size_t)n * cis + ci) * (size_t)Lin;
                    if (xl4 >= 0 && xl4 + 3 < Lin) {
                        v = *(const float4*)(xa + rb + xl4);
                        if (FLAGS & F_INB) u = *(const float4*)(xb + rb + xl4);
                    } else {
                        float* pv = (float*)&v;
                        float* pu = (float*)&u;
#pragma unroll
                        for (int t = 0; t < 4; ++t) {
                            int xl = xl4 + t;
                            if (xl >= 0 && xl < Lin) {
                                pv[t] = xa[rb + xl];
                                if (FLAGS & F_INB) pu[t] = xb[rb + xl];
                            }
                        }
                    }
                }
                va[p] = v;
                if (FLAGS & F_INB) vb[p] = u;
            }

            // ---- fused-bnp preamble (first tile only; overlaps loads) ----
            if (tt == 0) {
                if constexpr ((FLAGS & F_INBN) != 0) {
                    for (int c = tid; c < CI; c += 256) {
                        double mu  = sdA[c] * invA;
                        double var = sdA[CI + c] * invA - mu * mu;
                        double rs  = 1.0 / sqrt(var + 1e-5);
                        double gv  = (double)gA[c] * rs;
                        double bv  = (double)beA[c] - mu * gv;
                        sclA[c] = make_float2((float)gv, (float)bv);
                    }
                }
                if constexpr ((FLAGS & F_INBBN) != 0) {
                    for (int c = tid; c < CI; c += 256) {
                        double mu  = sdB[c] * invB;
                        double var = sdB[CI + c] * invB - mu * mu;
                        double rs  = 1.0 / sqrt(var + 1e-5);
                        double gv  = (double)gB[c] * rs;
                        double bv  = (double)beB[c] - mu * gv;
                        sclB[c] = make_float2((float)gv, (float)bv);
                    }
                }
                if constexpr ((FLAGS & F_ADDBN) != 0) {
                    for (int c = tid; c < CO; c += 256) {
                        double mu  = sdAdd[c] * invAdd;
                        double var = sdAdd[CO + c] * invAdd - mu * mu;
                        double rs  = 1.0 / sqrt(var + 1e-5);
                        double gv  = (double)gAdd[c] * rs;
                        double bv  = (double)beAdd[c] - mu * gv;
                        sclD[c] = make_float2((float)gv, (float)bv);
                    }
                }
            }
            if constexpr ((FLAGS & (F_INBN | F_INBBN | F_ADDBN)) != 0) {
                if (tt == 0) __syncthreads();   // scl* visible
            }

#pragma unroll
            for (int p = 0; p < PT; ++p) {
                int i = tid + p * 256;
                if (i < NTASK) {
                    int ci = i / NW;
                    int q  = i - ci * NW;
                    int xl4 = xw0 + 4 * q;
                    float4 v = va[p];
                    float* pv = (float*)&v;
                    if (FLAGS & F_INBN) {
                        float2 t = sclA[ci];
#pragma unroll
                        for (int e = 0; e < 4; ++e) pv[e] = pv[e] * t.x + t.y;
                    }
                    if (FLAGS & F_INRELU) {
#pragma unroll
                        for (int e = 0; e < 4; ++e) pv[e] = fmaxf(pv[e], 0.f);
                    }
                    if (FLAGS & F_INB) {
                        float4 u = vb[p];
                        float* pu = (float*)&u;
                        if (FLAGS & F_INBBN) {
                            float2 t = sclB[ci];
#pragma unroll
                            for (int e = 0; e < 4; ++e) {
                                float uu = pu[e] * t.x + t.y;
                                pv[e] += uu;
                            }
                        } else {
#pragma unroll
                            for (int e = 0; e < 4; ++e) pv[e] += pu[e];
                        }
                    }
                    // zero-padding: transforms must NOT touch OOB slots.
#pragma unroll
                    for (int e = 0; e < 4; ++e) {
                        int xl = xl4 + e;
                        if (xl < 0 || xl >= Lin) pv[e] = 0.f;
                    }
                    if constexpr (F4ST) {
                        *(float4*)&xs[ci * SPANP + 4 * q] = v;
                    } else {
#pragma unroll
                        for (int t = 0; t < 4; ++t) {
                            int s = 4 * q + t - ALN;
                            if (s >= 0 && s < SPAN) xs[ci * SPANP + s] = pv[t];
                        }
                    }
                }
            }
        }
        __syncthreads();

        float acc[CR][TLT];
#pragma unroll
        for (int cr = 0; cr < CR; ++cr) {
            float b = (FLAGS & F_BIAS) ? bias[co0 + cr] : 0.f;
#pragma unroll
            for (int j = 0; j < TLT; ++j) acc[cr][j] = b;
        }

        float xA[XR], xB[XR], wA[WR], wB[WR];

        auto ldx = [&](float* dst, int c) {
            const int base = c * SPANP + xoff;
#pragma unroll
            for (int g = 0; g < XR; g += 4) {
                const float* p = &xs[base + g];
#pragma unroll
                for (int t = 0; t < 4; ++t)
                    if (g + t < XR) dst[g + t] = p[t];
            }
        };
        auto ldw = [&](float* dst, int c) {
            const float* q = &wl[cog * WROW + c * WRP];
#pragma unroll
            for (int t = 0; t < WR; ++t) dst[t] = q[t];
        };
        auto dofma = [&](const float* xv, const float* wv) {
            if (MODE == 2) {
#pragma unroll
                for (int j = 0; j < TLT; ++j)
#pragma unroll
                    for (int cr = 0; cr < CR; ++cr)
                        acc[cr][j] += wv[(j & 1) * CR + cr] * xv[j >> 1];
            } else {
#pragma unroll
                for (int k = 0; k < K; ++k)
#pragma unroll
                    for (int j = 0; j < TLT; ++j)
#pragma unroll
                        for (int cr = 0; cr < CR; ++cr)
                            acc[cr][j] += wv[k * CR + cr]
                                        * xv[((MODE == 1) ? 2 * j : j) + k];
            }
        };

        if constexpr (K <= 3) {
            // register-double-buffered ci loop (CI even, >= 32)
            ldx(xA, 0); ldw(wA, 0);
            for (int ci = 0; ci + 2 < CI; ci += 2) {
                ldx(xB, ci + 1); ldw(wB, ci + 1);
                dofma(xA, wA);
                ldx(xA, ci + 2); ldw(wA, ci + 2);
                dofma(xB, wB);
            }
            ldx(xB, CI - 1); ldw(wB, CI - 1);
            dofma(xA, wA);
            dofma(xB, wB);
        } else {
#pragma unroll 2
            for (int ci = 0; ci < CI; ++ci) {
                ldx(xA, ci); ldw(wA, ci);
                dofma(xA, wA);
            }
        }

        // ---- epilogue: output-side add (opt BN), store, stats ----
        const int lo0 = ltile * TL + loOff;
#pragma unroll
        for (int cr = 0; cr < CR; ++cr) {
            size_t ob = ((size_t)n * CO + (co0 + cr)) * (size_t)Lout + lo0;
            if (FLAGS & F_ADD) {
                float2 t = (FLAGS & F_ADDBN) ? sclD[co0 + cr] : make_float2(1.f, 0.f);
                if constexpr (TLT % 4 == 0) {
#pragma unroll
                    for (int jv = 0; jv < TLT / 4; ++jv) {
                        float4 av = ((const float4*)(addsrc + ob))[jv];
                        float* a4 = &acc[cr][jv * 4];
                        if (FLAGS & F_ADDBN) {
                            a4[0] += av.x * t.x + t.y; a4[1] += av.y * t.x + t.y;
                            a4[2] += av.z * t.x + t.y; a4[3] += av.w * t.x + t.y;
                        } else {
                            a4[0] += av.x; a4[1] += av.y; a4[2] += av.z; a4[3] += av.w;
                        }
                    }
                } else {
#pragma unroll
                    for (int j = 0; j < TLT; ++j) {
                        float a = addsrc[ob + j];
                        acc[cr][j] += (FLAGS & F_ADDBN) ? (a * t.x + t.y) : a;
                    }
                }
            }
            if constexpr (TLT % 4 == 0) {
#pragma unroll
                for (int jv = 0; jv < TLT / 4; ++jv) {
                    float4 sv = make_float4(acc[cr][jv*4+0], acc[cr][jv*4+1],
                                            acc[cr][jv*4+2], acc[cr][jv*4+3]);
                    ((float4*)(yout + ob))[jv] = sv;
                }
            } else {
#pragma unroll
                for (int j = 0; j < TLT; ++j) yout[ob + j] = acc[cr][j];
            }
        }

        if (FLAGS & F_STATS) {
            float s1[CR], s2[CR];
#pragma unroll
            for (int cr = 0; cr < CR; ++cr) {
                s1[cr] = 0.f; s2[cr] = 0.f;
#pragma unroll
                for (int j = 0; j < TLT; ++j) {
                    s1[cr] += acc[cr][j];
                    s2[cr] += acc[cr][j] * acc[cr][j];
                }
            }
#pragma unroll
            for (int m = 1; m < LT; m <<= 1) {
#pragma unroll
                for (int cr = 0; cr < CR; ++cr) {
                    s1[cr] += __shfl_xor(s1[cr], m, 64);
                    s2[cr] += __shfl_xor(s2[cr], m, 64);
                }
            }
            if ((tid & (LT - 1)) == 0) {
#pragma unroll
                for (int cr = 0; cr < CR; ++cr) {
                    atomicAdd(&stats[co0 + cr],      (double)s1[cr]);
                    atomicAdd(&stats[CO + co0 + cr], (double)s2[cr]);
                }
            }
        }
    }
}

// ---------------------------------------------------------------------------
// VQ stage 1: grid 1024 = 512 row-groups x 2 codebook halves. 64 rows/block,
// 4 lanes/row split over dims (16/lane in regs). Expanded form:
// argmin_j (ww_j - 2 z.w_j); ww partials precomputed into the stride-68 pad.
// ---------------------------------------------------------------------------
__global__ __launch_bounds__(256)
void vq1_rF(const float* __restrict__ z, const float* __restrict__ emb,
            float* __restrict__ d0, float* __restrict__ d1,
            int* __restrict__ j0, int* __restrict__ j1)
{
    __shared__ float ws[128 * 68];
    const int tid  = threadIdx.x;
    const int sub  = tid & 3;
    const int half = blockIdx.x & 1;
    const int r    = (blockIdx.x >> 1) * 64 + (tid >> 2);

    const float4* zp = (const float4*)(z + (size_t)r * 64 + sub * 16);
    float4 z0 = zp[0], z1 = zp[1], z2 = zp[2], z3 = zp[3];

    float zzp = 0.f;
    zzp = fmaf(z0.x,z0.x,zzp); zzp = fmaf(z0.y,z0.y,zzp);
    zzp = fmaf(z0.z,z0.z,zzp); zzp = fmaf(z0.w,z0.w,zzp);
    zzp = fmaf(z1.x,z1.x,zzp); zzp = fmaf(z1.y,z1.y,zzp);
    zzp = fmaf(z1.z,z1.z,zzp); zzp = fmaf(z1.w,z1.w,zzp);
    zzp = fmaf(z2.x,z2.x,zzp); zzp = fmaf(z2.y,z2.y,zzp);
    zzp = fmaf(z2.z,z2.z,zzp); zzp = fmaf(z2.w,z2.w,zzp);
    zzp = fmaf(z3.x,z3.x,zzp); zzp = fmaf(z3.y,z3.y,zzp);
    zzp = fmaf(z3.z,z3.z,zzp); zzp = fmaf(z3.w,z3.w,zzp);

    float best = 3.4e38f;
    int   bj   = 0;
    for (int cc = 0; cc < 2; ++cc) {
        const int c0 = half * 256 + cc * 128;
        __syncthreads();
        for (int i = tid; i < 128 * 16; i += 256) {
            int j = i >> 4, q = i & 15;
            ((float4*)ws)[j * 17 + q] = ((const float4*)(emb + c0 * 64))[i];
        }
        __syncthreads();
        for (int i = tid; i < 512; i += 256) {
            int j = i >> 2, s = i & 3;
            const float4* p = (const float4*)&ws[j * 68 + s * 16];
            float4 a = p[0], b = p[1], c = p[2], d = p[3];
            float ww = 0.f;
            ww = fmaf(a.x,a.x,ww); ww = fmaf(a.y,a.y,ww);
            ww = fmaf(a.z,a.z,ww); ww = fmaf(a.w,a.w,ww);
            ww = fmaf(b.x,b.x,ww); ww = fmaf(b.y,b.y,ww);
            ww = fmaf(b.z,b.z,ww); ww = fmaf(b.w,b.w,ww);
            ww = fmaf(c.x,c.x,ww); ww = fmaf(c.y,c.y,ww);
            ww = fmaf(c.z,c.z,ww); ww = fmaf(c.w,c.w,ww);
            ww = fmaf(d.x,d.x,ww); ww = fmaf(d.y,d.y,ww);
            ww = fmaf(d.z,d.z,ww); ww = fmaf(d.w,d.w,ww);
            ws[j * 68 + 64 + s] = ww;
        }
        __syncthreads();
        for (int j = 0; j < 128; ++j) {
            const float4* wp = (const float4*)&ws[j * 68 + sub * 16];
            float4 w0 = wp[0], w1 = wp[1], w2 = wp[2], w3 = wp[3];
            float dot = 0.f;
            dot = fmaf(z0.x,w0.x,dot); dot = fmaf(z0.y,w0.y,dot);
            dot = fmaf(z0.z,w0.z,dot); dot = fmaf(z0.w,w0.w,dot);
            dot = fmaf(z1.x,w1.x,dot); dot = fmaf(z1.y,w1.y,dot);
            dot = fmaf(z1.z,w1.z,dot); dot = fmaf(z1.w,w1.w,dot);
            dot = fmaf(z2.x,w2.x,dot); dot = fmaf(z2.y,w2.y,dot);
            dot = fmaf(z2.z,w2.z,dot); dot = fmaf(z2.w,w2.w,dot);
            dot = fmaf(z3.x,w3.x,dot); dot = fmaf(z3.y,w3.y,dot);
            dot = fmaf(z3.z,w3.z,dot); dot = fmaf(z3.w,w3.w,dot);
            float t = fmaf(dot, -2.f, ws[j * 68 + 64 + sub]);
            t += __shfl_xor(t, 1, 64);
            t += __shfl_xor(t, 2, 64);
            if (t < best) { best = t; bj = c0 + j; }
        }
    }

    float zz = zzp;
    zz += __shfl_xor(zz, 1, 64);
    zz += __shfl_xor(zz, 2, 64);

    if (sub == 0) {
        if (half) { d1[r] = zz + best; j1[r] = bj; }
        else      { d0[r] = zz + best; j0[r] = bj; }
    }
}

// VQ stage 2: combine halves, gather hq rows, accumulate loss.
__global__ __launch_bounds__(256)
void vq2_rF(const float* __restrict__ d0, const float* __restrict__ d1,
            const int* __restrict__ j0, const int* __restrict__ j1,
            const float* __restrict__ emb, float* __restrict__ hq,
            double* __restrict__ lossAcc)
{
    const int r = blockIdx.x * 256 + threadIdx.x;
    float da = d0[r], db = d1[r];
    bool pick1 = db < da;                    // ties -> half 0 (lower index)
    float d = pick1 ? db : da;
    int   j = pick1 ? j1[r] : j0[r];

    const float4* ep = (const float4*)(emb + (size_t)j * 64);
    float4* hp = (float4*)(hq + (size_t)r * 64);
#pragma unroll
    for (int t = 0; t < 16; ++t) hp[t] = ep[t];

    float s = d;
#pragma unroll
    for (int m = 1; m < 64; m <<= 1) s += __shfl_xor(s, m, 64);
    if ((threadIdx.x & 63) == 0) atomicAdd(lossAcc, (double)s);
}

__global__ void zd_rD(double* p, int n) {
    int i = blockIdx.x * 256 + threadIdx.x;
    if (i < n) p[i] = 0.0;
}

__global__ void wsguard_rD(float* p, int n) {
    int i = blockIdx.x * 256 + threadIdx.x;
    if (i < n) p[i] = 1000.0f;
}

__global__ void lossfin_rD(const double* acc, float* out) {
    float m = (float)(acc[0] * (1.0 / 32768.0));
    out[2097152] = m;   // commit_loss
    out[2097153] = m;   // vq_loss
}

extern "C" void kernel_launch(void* const* d_in, const int* in_sizes, int n_in,
                              void* d_out, int out_size, void* d_ws, size_t ws_size,
                              hipStream_t stream)
{
    const size_t NEED = (size_t)3 * 4194304 * 4 + 2305 * 8 + 1152 * 8 + 64;
    if (ws_size < NEED) {
        wsguard_rD<<<dim3((out_size + 255) / 256), 256, 0, stream>>>((float*)d_out, out_size);
        return;
    }

    const float* x        = (const float*)d_in[0];
    const float* w_conv   = (const float*)d_in[1];
    const float* b_conv   = (const float*)d_in[2];
    const float* g_conv   = (const float*)d_in[3];
    const float* be_conv  = (const float*)d_in[4];
    const float* w_r1     = (const float*)d_in[5];
    const float* b_r1     = (const float*)d_in[6];
    const float* g_r1     = (const float*)d_in[7];
    const float* be_r1    = (const float*)d_in[8];
    const float* w_ds1    = (const float*)d_in[9];
    const float* b_ds1    = (const float*)d_in[10];
    const float* w_r2     = (const float*)d_in[11];
    const float* b_r2     = (const float*)d_in[12];
    const float* g_r2     = (const float*)d_in[13];
    const float* be_r2    = (const float*)d_in[14];
    const float* w_1to2   = (const float*)d_in[15];
    const float* w_ds2    = (const float*)d_in[16];
    const float* b_ds2    = (const float*)d_in[17];
    const float* embed_w  = (const float*)d_in[18];
    const float* w_us2    = (const float*)d_in[19];
    const float* b_us2    = (const float*)d_in[20];
    const float* w_dr2    = (const float*)d_in[21];
    const float* b_dr2    = (const float*)d_in[22];
    const float* g_dr2    = (const float*)d_in[23];
    const float* be_dr2   = (const float*)d_in[24];
    const float* w_2to1   = (const float*)d_in[25];
    const float* w_us1    = (const float*)d_in[26];
    const float* b_us1    = (const float*)d_in[27];
    const float* w_dr1    = (const float*)d_in[28];
    const float* b_dr1    = (const float*)d_in[29];
    const float* g_dr1    = (const float*)d_in[30];
    const float* be_dr1   = (const float*)d_in[31];
    const float* w_deconv = (const float*)d_in[32];
    const float* b_deconv = (const float*)d_in[33];

    float* out = (float*)d_out;

    float*  B0 = (float*)d_ws;
    float*  B1 = B0 + 4194304;
    float*  B2 = B0 + 2 * 4194304;
    double* SD = (double*)(B0 + 3 * 4194304);
    double* lossAcc = SD + 9 * 256;

    // VQ scratch lives in B0 (free between ds2 and us2)
    float* vqd0 = B0;
    float* vqd1 = B0 + 32768;
    int*   vqj0 = (int*)(B0 + 65536);
    int*   vqj1 = (int*)(B0 + 98304);

    const int N = 64;
    const double i64k = 1.0 / 65536.0;
    const double i32k = 1.0 / 32768.0;
    const float*  NOF = nullptr;
    const double* NOD = nullptr;

    zd_rD<<<dim3(10), 256, 0, stream>>>(SD, 9 * 256 + 1);

    // ---- encoder ----
    conv_rO<32,64,7,0,128,32,4,3,2, F_BIAS|F_STATS>
        <<<dim3(4, N, 2), 256, 0, stream>>>(x, NOD, NOF, NOF, NOF, NOD, NOF, NOF,
            w_conv, b_conv, NOF, NOD, NOF, NOF, SD+0*256, B0,
            1024, 1024, 32, 32, 0.0, 0.0, 0.0);

    conv_rO<64,64,3,0,128,32,4,1,2, F_BIAS|F_STATS|F_INBN>
        <<<dim3(4, N, 2), 256, 0, stream>>>(B0, SD+0*256, g_conv, be_conv,
            NOF, NOD, NOF, NOF, w_r1, b_r1, NOF, NOD, NOF, NOF, SD+1*256, B1,
            1024, 1024, 64, 64, i64k, 0.0, 0.0);

    conv_rO<64,64,3,0,128,32,4,1,2, F_BIAS|F_STATS|F_INBN|F_INRELU>
        <<<dim3(4, N, 2), 256, 0, stream>>>(B1, SD+1*256, g_r1, be_r1,
            NOF, NOD, NOF, NOF, w_r1+12288, b_r1+64, NOF, NOD, NOF, NOF, SD+2*256, B2,
            1024, 1024, 64, 64, i64k, 0.0, 0.0);

    conv_rO<64,64,3,0,128,32,4,1,2, F_BIAS|F_STATS|F_INBN|F_INRELU>
        <<<dim3(4, N, 2), 256, 0, stream>>>(B2, SD+2*256, g_r1+64, be_r1+64,
            NOF, NOD, NOF, NOF, w_r1+24576, b_r1+128, NOF, NOD, NOF, NOF, SD+3*256, B1,
            1024, 1024, 64, 64, i64k, 0.0, 0.0);

    // ds1: input = bn3(B1) + bn0(B0) -> stride-2 conv -> B2
    conv_rO<64,64,2,1,64,32,4,0,2, F_BIAS|F_INBN|F_INB|F_INBBN>
        <<<dim3(4, N, 2), 256, 0, stream>>>(B1, SD+3*256, g_r1+128, be_r1+128,
            B0, SD+0*256, g_conv, be_conv, w_ds1, b_ds1, NOF, NOD, NOF, NOF,
            nullptr, B2, 1024, 512, 64, 64, i64k, i64k, 0.0);

    conv_rO<64,128,3,0,128,32,4,1,2, F_BIAS|F_STATS>
        <<<dim3(2, N, 4), 256, 0, stream>>>(B2, NOD, NOF, NOF, NOF, NOD, NOF, NOF,
            w_r2, b_r2, NOF, NOD, NOF, NOF, SD+4*256, B1,
            512, 512, 64, 64, 0.0, 0.0, 0.0);

    // 1to2: conv(B2,w_1to2) + bn4(B1) -> B0  (w_1to2 is (O=128,I=64,K=1) -> wci=64)
    conv_rO<64,128,1,0,128,32,4,0,2, F_ADD|F_ADDBN>
        <<<dim3(2, N, 4), 256, 0, stream>>>(B2, NOD, NOF, NOF, NOF, NOD, NOF, NOF,
            w_1to2, NOF, B1, SD+4*256, g_r2, be_r2, nullptr, B0,
            512, 512, 64, 64, 0.0, 0.0, i32k);

    // ds2: B0 -> stride-2 conv -> B1
    conv_rO<128,128,2,1,32,32,4,0,2, F_BIAS>
        <<<dim3(4, N, 4), 256, 0, stream>>>(B0, NOD, NOF, NOF, NOF, NOD, NOF, NOF,
            w_ds2, b_ds2, NOF, NOD, NOF, NOF, nullptr, B1,
            512, 256, 128, 128, 0.0, 0.0, 0.0);

    // ---- vector quantization ----
    vq1_rF<<<dim3(1024), 256, 0, stream>>>(B1, embed_w, vqd0, vqd1, vqj0, vqj1);
    vq2_rF<<<dim3(128), 256, 0, stream>>>(vqd0, vqd1, vqj0, vqj1, embed_w, B2, lossAcc);
    lossfin_rD<<<1, 1, 0, stream>>>(lossAcc, out);

    // ---- decoder ----
    // us2: B2(hq) -> transposed stride-2 -> B0
    conv_rO<128,128,2,2,128,32,4,0,2, F_BIAS>
        <<<dim3(2, N, 4), 256, 0, stream>>>(B2, NOD, NOF, NOF, NOF, NOD, NOF, NOF,
            w_us2, b_us2, NOF, NOD, NOF, NOF, nullptr, B0,
            256, 512, 128, 128, 0.0, 0.0, 0.0);

    // dr2 (CI=128 split 2x64): a = ci 0..63 + bias -> B1 (512 blocks, NT=1)
    conv_rO<64,64,3,0,128,32,4,1,1, F_WT|F_BIAS>
        <<<dim3(4, N, 2), 256, 0, stream>>>(B0, NOD, NOF, NOF, NOF, NOD, NOF, NOF,
            w_dr2, b_dr2, NOF, NOD, NOF, NOF, nullptr, B1,
            512, 512, 128, 64, 0.0, 0.0, 0.0);
    conv_rO<64,64,3,0,128,32,4,1,1, F_WT|F_STATS|F_ADD>
        <<<dim3(4, N, 2), 256, 0, stream>>>(B0 + (size_t)64*512, NOD, NOF, NOF,
            NOF, NOD, NOF, NOF, w_dr2 + 64*64*3, NOF, B1, NOD, NOF, NOF,
            SD+5*256, B1, 512, 512, 128, 64, 0.0, 0.0, 0.0);

    // 2to1 (CI=128 split): a = conv(ci 0..63) + bn5(B1) -> B2 (512 blocks, NT=1)
    conv_rO<64,64,1,0,128,32,4,0,1, F_ADD|F_ADDBN>
        <<<dim3(4, N, 2), 256, 0, stream>>>(B0, NOD, NOF, NOF, NOF, NOD, NOF, NOF,
            w_2to1, NOF, B1, SD+5*256, g_dr2, be_dr2, nullptr, B2,
            512, 512, 128, 128, 0.0, 0.0, i32k);
    conv_rO<64,64,1,0,128,32,4,0,1, F_ADD>
        <<<dim3(4, N, 2), 256, 0, stream>>>(B0 + (size_t)64*512, NOD, NOF, NOF,
            NOF, NOD, NOF, NOF, w_2to1 + 64, NOF, B2, NOD, NOF, NOF,
            nullptr, B2, 512, 512, 128, 128, 0.0, 0.0, 0.0);

    // us1: B2 -> transposed stride-2 -> B0 (t, kept raw for final skip)
    conv_rO<64,64,2,2,128,32,4,0,2, F_BIAS>
        <<<dim3(4, N, 2), 256, 0, stream>>>(B2, NOD, NOF, NOF, NOF, NOD, NOF, NOF,
            w_us1, b_us1, NOF, NOD, NOF, NOF, nullptr, B0,
            512, 1024, 64, 64, 0.0, 0.0, 0.0);

    conv_rO<64,64,3,0,128,32,4,1,2, F_WT|F_BIAS|F_STATS>
        <<<dim3(4, N, 2), 256, 0, stream>>>(B0, NOD, NOF, NOF, NOF, NOD, NOF, NOF,
            w_dr1, b_dr1, NOF, NOD, NOF, NOF, SD+6*256, B1,
            1024, 1024, 64, 64, 0.0, 0.0, 0.0);

    conv_rO<64,64,3,0,128,32,4,1,2, F_WT|F_BIAS|F_STATS|F_INBN|F_INRELU>
        <<<dim3(4, N, 2), 256, 0, stream>>>(B1, SD+6*256, g_dr1, be_dr1,
            NOF, NOD, NOF, NOF, w_dr1+12288, b_dr1+64, NOF, NOD, NOF, NOF,
            SD+7*256, B2, 1024, 1024, 64, 64, i64k, 0.0, 0.0);

    conv_rO<64,64,3,0,128,32,4,1,2, F_WT|F_BIAS|F_STATS|F_INBN|F_INRELU>
        <<<dim3(4, N, 2), 256, 0, stream>>>(B2, SD+7*256, g_dr1+64, be_dr1+64,
            NOF, NOD, NOF, NOF, w_dr1+24576, b_dr1+128, NOF, NOD, NOF, NOF,
            SD+8*256, B1, 1024, 1024, 64, 64, i64k, 0.0, 0.0);

    // deconv: input = bn8(B1) + B0 raw -> convT K=7 -> out
    conv_rO<64,32,7,0,128,16,4,3,2, F_WT|F_BIAS|F_INBN|F_INB>
        <<<dim3(4, N, 2), 256, 0, stream>>>(B1, SD+8*256, g_dr1+128, be_dr1+128,
            B0, NOD, NOF, NOF, w_deconv, b_deconv, NOF, NOD, NOF, NOF,
            nullptr, out, 1024, 1024, 64, 64, i64k, 0.0, 0.0);
}

// Round 13
// 987.986 us; speedup vs baseline: 1.6585x; 1.0210x over previous
//
// ===========================================================================
// R26 — R25 (1009us) with TL=256 on the six hot K=3 CI=64 L=1024 convs only
// (r1#1-3, dr1#1-3): TLT 4->8 halves LDS-cycles-per-FMA (weight reads are
// the dominant LDS cost; amortization factor = TLT). COB stays 32 (staging
// volume unchanged — R15's regression was COB=16's 4x staging, not TL).
// TLT=8 => stride-32B lane reads = 4-way bank conflict => re-add R14's
// proven XOR swizzle (st ^= (st>>3)&4) on store+load. LDS 92KB -> 1 blk/CU.
// Everything else (incl. VQ) identical to R25.
// ===========================================================================
#include <hip/hip_runtime.h>
#include <stdint.h>

#define F_WT     1
#define F_STATS  2
#define F_BIAS   4
#define F_INBN   8
#define F_INRELU 16
#define F_INB    32
#define F_INBBN  64
#define F_ADD    128
#define F_ADDBN  256

// ---------------------------------------------------------------------------
// Tiled conv, CR outputs/thread in channel dim, NT tiles per block.
// MODE 0: stride-1 (PAD template), WT: ConvTranspose (I,O,K) flipped.
// MODE 1: stride-2 downsample K=2. MODE 2: stride-2 transposed upsample K=2.
// 256 thr = NCG(=COB/CR) co-groups x LT(=256/NCG) l-groups, TLT=TL/LT.
// BN scales computed per-block from double stats (fused bnp).
// ---------------------------------------------------------------------------
template<int CI, int CO, int K, int MODE, int TL, int COB, int CR, int PAD,
         int NT, int FLAGS>
__global__ __launch_bounds__(256)
void conv_rP(const float* __restrict__ xa,
             const double* __restrict__ sdA, const float* __restrict__ gA,
             const float* __restrict__ beA,
             const float* __restrict__ xb,
             const double* __restrict__ sdB, const float* __restrict__ gB,
             const float* __restrict__ beB,
             const float* __restrict__ w,  const float* __restrict__ bias,
             const float* __restrict__ addsrc,
             const double* __restrict__ sdAdd, const float* __restrict__ gAdd,
             const float* __restrict__ beAdd,
             double* __restrict__ stats, float* __restrict__ yout,
             int Lin, int Lout, int cis, int wci,
             double invA, double invB, double invAdd)
{
    constexpr int NCG  = COB / CR;          // co groups
    constexpr int LT   = 256 / NCG;         // l groups
    constexpr int TLT  = TL / LT;           // outputs per thread per co
    constexpr int SPAN = (MODE == 0) ? (TL + K - 1)
                       : (MODE == 1) ? ((TL - 1) * 2 + K)
                       : (TL / 2);
    constexpr int SPANP = (SPAN + 3) & ~3;
    constexpr int WR    = K * CR;
    constexpr int WRP   = (WR + 3) & ~3;
    constexpr int WROW  = CI * WRP + 4;     // +4 float stagger per cog
    constexpr int XR    = (MODE == 0) ? (TLT + K - 1)
                        : (MODE == 1) ? ((TLT - 1) * 2 + K)
                        : ((TLT + 1) / 2);
    // stride-32B lane reads (TLT=8, MODE0) are a 4-way quad conflict: swizzle
    constexpr bool SWZ  = (MODE == 0 && TLT == 8);
    // aligned-window shift: x0 = ltile*stride - PAD; ALN makes loads 16B-aligned
    constexpr int ALN  = (MODE == 0) ? ((4 - (PAD & 3)) & 3) : 0;
    constexpr int NW   = (SPAN + ALN + 3) / 4;     // f4 loads per row
    constexpr int NTASK = CI * NW;
    constexpr int PT    = (NTASK + 255) / 256;
    constexpr bool F4ST = (ALN == 0) && (SPAN % 4 == 0);
    constexpr int WNT   = NCG * CI * WR;
    constexpr int WPT   = (WNT + 255) / 256;

    __shared__ float xs[CI * SPANP];
    __shared__ float wl[NCG * WROW];
    __shared__ float2 sclA[(FLAGS & F_INBN)  ? CI : 1];
    __shared__ float2 sclB[(FLAGS & F_INBBN) ? CI : 1];
    __shared__ float2 sclD[(FLAGS & F_ADDBN) ? CO : 1];

    const int tid    = threadIdx.x;
    const int n      = blockIdx.y;
    const int coBase = blockIdx.z * COB;

    // ---- weights -> LDS (once per block; tile-invariant) ----
    {
        float wvv[WPT];
#pragma unroll
        for (int p = 0; p < WPT; ++p) {
            int i = tid + p * 256;
            float v = 0.f;
            if (i < WNT) {
                int cogi = i / (CI * WR);
                int rem  = i - cogi * (CI * WR);
                int ci   = rem / WR;
                int rem2 = rem - ci * WR;
                int k    = rem2 / CR;
                int cr   = rem2 - k * CR;
                int co   = coBase + cogi * CR + cr;
                int src;
                if (FLAGS & F_WT)   src = (ci * CO + co) * K + (K - 1 - k);
                else if (MODE == 2) src = (ci * CO + co) * K + k;
                else                src = (co * wci + ci) * K + k;
                v = w[src];
            }
            wvv[p] = v;
        }
#pragma unroll
        for (int p = 0; p < WPT; ++p) {
            int i = tid + p * 256;
            if (i < WNT) {
                int cogi = i / (CI * WR);
                int rem  = i - cogi * (CI * WR);
                int ci   = rem / WR;
                int rem2 = rem - ci * WR;
                int k    = rem2 / CR;
                int cr   = rem2 - k * CR;
                wl[cogi * WROW + ci * WRP + k * CR + cr] = wvv[p];
            }
        }
    }

    const int cog   = tid / LT;
    const int lg    = tid % LT;
    const int co0   = coBase + cog * CR;
    const int loOff = lg * TLT;
    const int xoff  = (MODE == 1) ? loOff * 2
                    : (MODE == 2) ? (loOff >> 1) : loOff;

    for (int tt = 0; tt < NT; ++tt) {
        const int ltile = blockIdx.x * NT + tt;
        if (tt > 0) __syncthreads();      // prior tile's xs reads complete

        int x0;
        if (MODE == 0)      x0 = ltile * TL - PAD;
        else if (MODE == 1) x0 = ltile * TL * 2;
        else                x0 = ltile * (TL / 2);
        const int xw0 = x0 - ALN;         // aligned window start

        {
            float4 va[PT];
            float4 vb[PT];
#pragma unroll
            for (int p = 0; p < PT; ++p) {
                int i = tid + p * 256;
                float4 v = make_float4(0.f, 0.f, 0.f, 0.f);
                float4 u = make_float4(0.f, 0.f, 0.f, 0.f);
                if (i < NTASK) {
                    int ci  = i / NW;
                    int q   = i - ci * NW;
                    int xl4 = xw0 + 4 * q;
                    size_t rb = ((size_t)n * cis + ci) * (size_t)Lin;
                    if (xl4 >= 0 && xl4 + 3 < Lin) {
                        v = *(const float4*)(xa + rb + xl4);
                        if (FLAGS & F_INB) u = *(const float4*)(xb + rb + xl4);
                    } else {
                        float* pv = (float*)&v;
                        float* pu = (float*)&u;
#pragma unroll
                        for (int t = 0; t < 4; ++t) {
                            int xl = xl4 + t;
                            if (xl >= 0 && xl < Lin) {
                                pv[t] = xa[rb + xl];
                                if (FLAGS & F_INB) pu[t] = xb[rb + xl];
                            }
                        }
                    }
                }
                va[p] = v;
                if (FLAGS & F_INB) vb[p] = u;
            }

            // ---- fused-bnp preamble (first tile only; overlaps loads) ----
            if (tt == 0) {
                if constexpr ((FLAGS & F_INBN) != 0) {
                    for (int c = tid; c < CI; c += 256) {
                        double mu  = sdA[c] * invA;
                        double var = sdA[CI + c] * invA - mu * mu;
                        double rs  = 1.0 / sqrt(var + 1e-5);
                        double gv  = (double)gA[c] * rs;
                        double bv  = (double)beA[c] - mu * gv;
                        sclA[c] = make_float2((float)gv, (float)bv);
                    }
                }
                if constexpr ((FLAGS & F_INBBN) != 0) {
                    for (int c = tid; c < CI; c += 256) {
                        double mu  = sdB[c] * invB;
                        double var = sdB[CI + c] * invB - mu * mu;
                        double rs  = 1.0 / sqrt(var + 1e-5);
                        double gv  = (double)gB[c] * rs;
                        double bv  = (double)beB[c] - mu * gv;
                        sclB[c] = make_float2((float)gv, (float)bv);
                    }
                }
                if constexpr ((FLAGS & F_ADDBN) != 0) {
                    for (int c = tid; c < CO; c += 256) {
                        double mu  = sdAdd[c] * invAdd;
                        double var = sdAdd[CO + c] * invAdd - mu * mu;
                        double rs  = 1.0 / sqrt(var + 1e-5);
                        double gv  = (double)gAdd[c] * rs;
                        double bv  = (double)beAdd[c] - mu * gv;
                        sclD[c] = make_float2((float)gv, (float)bv);
                    }
                }
            }
            if constexpr ((FLAGS & (F_INBN | F_INBBN | F_ADDBN)) != 0) {
                if (tt == 0) __syncthreads();   // scl* visible
            }

#pragma unroll
            for (int p = 0; p < PT; ++p) {
                int i = tid + p * 256;
                if (i < NTASK) {
                    int ci = i / NW;
                    int q  = i - ci * NW;
                    int xl4 = xw0 + 4 * q;
                    float4 v = va[p];
                    float* pv = (float*)&v;
                    if (FLAGS & F_INBN) {
                        float2 t = sclA[ci];
#pragma unroll
                        for (int e = 0; e < 4; ++e) pv[e] = pv[e] * t.x + t.y;
                    }
                    if (FLAGS & F_INRELU) {
#pragma unroll
                        for (int e = 0; e < 4; ++e) pv[e] = fmaxf(pv[e], 0.f);
                    }
                    if (FLAGS & F_INB) {
                        float4 u = vb[p];
                        float* pu = (float*)&u;
                        if (FLAGS & F_INBBN) {
                            float2 t = sclB[ci];
#pragma unroll
                            for (int e = 0; e < 4; ++e) {
                                float uu = pu[e] * t.x + t.y;
                                pv[e] += uu;
                            }
                        } else {
#pragma unroll
                            for (int e = 0; e < 4; ++e) pv[e] += pu[e];
                        }
                    }
                    // zero-padding: transforms must NOT touch OOB slots.
#pragma unroll
                    for (int e = 0; e < 4; ++e) {
                        int xl = xl4 + e;
                        if (xl < 0 || xl >= Lin) pv[e] = 0.f;
                    }
                    if constexpr (F4ST) {
                        int st4 = ci * SPANP + 4 * q;
                        if (SWZ) st4 ^= (st4 >> 3) & 4;
                        *(float4*)&xs[st4] = v;
                    } else {
#pragma unroll
                        for (int t = 0; t < 4; ++t) {
                            int s = 4 * q + t - ALN;
                            if (s >= 0 && s < SPAN) {
                                int st = ci * SPANP + s;
                                if (SWZ) st ^= (st >> 3) & 4;
                                xs[st] = pv[t];
                            }
                        }
                    }
                }
            }
        }
        __syncthreads();

        float acc[CR][TLT];
#pragma unroll
        for (int cr = 0; cr < CR; ++cr) {
            float b = (FLAGS & F_BIAS) ? bias[co0 + cr] : 0.f;
#pragma unroll
            for (int j = 0; j < TLT; ++j) acc[cr][j] = b;
        }

        float xA[XR], xB[XR], wA[WR], wB[WR];

        auto ldx = [&](float* dst, int c) {
            const int base = c * SPANP + xoff;
#pragma unroll
            for (int g = 0; g < XR; g += 4) {
                int pb = base + g;
                if (SWZ) pb ^= (pb >> 3) & 4;
                const float* p = &xs[pb];
#pragma unroll
                for (int t = 0; t < 4; ++t)
                    if (g + t < XR) dst[g + t] = p[t];
            }
        };
        auto ldw = [&](float* dst, int c) {
            const float* q = &wl[cog * WROW + c * WRP];
#pragma unroll
            for (int t = 0; t < WR; ++t) dst[t] = q[t];
        };
        auto dofma = [&](const float* xv, const float* wv) {
            if (MODE == 2) {
#pragma unroll
                for (int j = 0; j < TLT; ++j)
#pragma unroll
                    for (int cr = 0; cr < CR; ++cr)
                        acc[cr][j] += wv[(j & 1) * CR + cr] * xv[j >> 1];
            } else {
#pragma unroll
                for (int k = 0; k < K; ++k)
#pragma unroll
                    for (int j = 0; j < TLT; ++j)
#pragma unroll
                        for (int cr = 0; cr < CR; ++cr)
                            acc[cr][j] += wv[k * CR + cr]
                                        * xv[((MODE == 1) ? 2 * j : j) + k];
            }
        };

        if constexpr (K <= 3) {
            // register-double-buffered ci loop (CI even, >= 32)
            ldx(xA, 0); ldw(wA, 0);
            for (int ci = 0; ci + 2 < CI; ci += 2) {
                ldx(xB, ci + 1); ldw(wB, ci + 1);
                dofma(xA, wA);
                ldx(xA, ci + 2); ldw(wA, ci + 2);
                dofma(xB, wB);
            }
            ldx(xB, CI - 1); ldw(wB, CI - 1);
            dofma(xA, wA);
            dofma(xB, wB);
        } else {
#pragma unroll 2
            for (int ci = 0; ci < CI; ++ci) {
                ldx(xA, ci); ldw(wA, ci);
                dofma(xA, wA);
            }
        }

        // ---- epilogue: output-side add (opt BN), store, stats ----
        const int lo0 = ltile * TL + loOff;
#pragma unroll
        for (int cr = 0; cr < CR; ++cr) {
            size_t ob = ((size_t)n * CO + (co0 + cr)) * (size_t)Lout + lo0;
            if (FLAGS & F_ADD) {
                float2 t = (FLAGS & F_ADDBN) ? sclD[co0 + cr] : make_float2(1.f, 0.f);
                if constexpr (TLT % 4 == 0) {
#pragma unroll
                    for (int jv = 0; jv < TLT / 4; ++jv) {
                        float4 av = ((const float4*)(addsrc + ob))[jv];
                        float* a4 = &acc[cr][jv * 4];
                        if (FLAGS & F_ADDBN) {
                            a4[0] += av.x * t.x + t.y; a4[1] += av.y * t.x + t.y;
                            a4[2] += av.z * t.x + t.y; a4[3] += av.w * t.x + t.y;
                        } else {
                            a4[0] += av.x; a4[1] += av.y; a4[2] += av.z; a4[3] += av.w;
                        }
                    }
                } else {
#pragma unroll
                    for (int j = 0; j < TLT; ++j) {
                        float a = addsrc[ob + j];
                        acc[cr][j] += (FLAGS & F_ADDBN) ? (a * t.x + t.y) : a;
                    }
                }
            }
            if constexpr (TLT % 4 == 0) {
#pragma unroll
                for (int jv = 0; jv < TLT / 4; ++jv) {
                    float4 sv = make_float4(acc[cr][jv*4+0], acc[cr][jv*4+1],
                                            acc[cr][jv*4+2], acc[cr][jv*4+3]);
                    ((float4*)(yout + ob))[jv] = sv;
                }
            } else {
#pragma unroll
                for (int j = 0; j < TLT; ++j) yout[ob + j] = acc[cr][j];
            }
        }

        if (FLAGS & F_STATS) {
            float s1[CR], s2[CR];
#pragma unroll
            for (int cr = 0; cr < CR; ++cr) {
                s1[cr] = 0.f; s2[cr] = 0.f;
#pragma unroll
                for (int j = 0; j < TLT; ++j) {
                    s1[cr] += acc[cr][j];
                    s2[cr] += acc[cr][j] * acc[cr][j];
                }
            }
#pragma unroll
            for (int m = 1; m < LT; m <<= 1) {
#pragma unroll
                for (int cr = 0; cr < CR; ++cr) {
                    s1[cr] += __shfl_xor(s1[cr], m, 64);
                    s2[cr] += __shfl_xor(s2[cr], m, 64);
                }
            }
            if ((tid & (LT - 1)) == 0) {
#pragma unroll
                for (int cr = 0; cr < CR; ++cr) {
                    atomicAdd(&stats[co0 + cr],      (double)s1[cr]);
                    atomicAdd(&stats[CO + co0 + cr], (double)s2[cr]);
                }
            }
        }
    }
}

// ---------------------------------------------------------------------------
// VQ stage 1: grid 1024 = 512 row-groups x 2 codebook halves. 64 rows/block,
// 4 lanes/row split over dims (16/lane in regs). Expanded form:
// argmin_j (ww_j - 2 z.w_j); ww partials precomputed into the stride-68 pad.
// ---------------------------------------------------------------------------
__global__ __launch_bounds__(256)
void vq1_rF(const float* __restrict__ z, const float* __restrict__ emb,
            float* __restrict__ d0, float* __restrict__ d1,
            int* __restrict__ j0, int* __restrict__ j1)
{
    __shared__ float ws[128 * 68];
    const int tid  = threadIdx.x;
    const int sub  = tid & 3;
    const int half = blockIdx.x & 1;
    const int r    = (blockIdx.x >> 1) * 64 + (tid >> 2);

    const float4* zp = (const float4*)(z + (size_t)r * 64 + sub * 16);
    float4 z0 = zp[0], z1 = zp[1], z2 = zp[2], z3 = zp[3];

    float zzp = 0.f;
    zzp = fmaf(z0.x,z0.x,zzp); zzp = fmaf(z0.y,z0.y,zzp);
    zzp = fmaf(z0.z,z0.z,zzp); zzp = fmaf(z0.w,z0.w,zzp);
    zzp = fmaf(z1.x,z1.x,zzp); zzp = fmaf(z1.y,z1.y,zzp);
    zzp = fmaf(z1.z,z1.z,zzp); zzp = fmaf(z1.w,z1.w,zzp);
    zzp = fmaf(z2.x,z2.x,zzp); zzp = fmaf(z2.y,z2.y,zzp);
    zzp = fmaf(z2.z,z2.z,zzp); zzp = fmaf(z2.w,z2.w,zzp);
    zzp = fmaf(z3.x,z3.x,zzp); zzp = fmaf(z3.y,z3.y,zzp);
    zzp = fmaf(z3.z,z3.z,zzp); zzp = fmaf(z3.w,z3.w,zzp);

    float best = 3.4e38f;
    int   bj   = 0;
    for (int cc = 0; cc < 2; ++cc) {
        const int c0 = half * 256 + cc * 128;
        __syncthreads();
        for (int i = tid; i < 128 * 16; i += 256) {
            int j = i >> 4, q = i & 15;
            ((float4*)ws)[j * 17 + q] = ((const float4*)(emb + c0 * 64))[i];
        }
        __syncthreads();
        for (int i = tid; i < 512; i += 256) {
            int j = i >> 2, s = i & 3;
            const float4* p = (const float4*)&ws[j * 68 + s * 16];
            float4 a = p[0], b = p[1], c = p[2], d = p[3];
            float ww = 0.f;
            ww = fmaf(a.x,a.x,ww); ww = fmaf(a.y,a.y,ww);
            ww = fmaf(a.z,a.z,ww); ww = fmaf(a.w,a.w,ww);
            ww = fmaf(b.x,b.x,ww); ww = fmaf(b.y,b.y,ww);
            ww = fmaf(b.z,b.z,ww); ww = fmaf(b.w,b.w,ww);
            ww = fmaf(c.x,c.x,ww); ww = fmaf(c.y,c.y,ww);
            ww = fmaf(c.z,c.z,ww); ww = fmaf(c.w,c.w,ww);
            ww = fmaf(d.x,d.x,ww); ww = fmaf(d.y,d.y,ww);
            ww = fmaf(d.z,d.z,ww); ww = fmaf(d.w,d.w,ww);
            ws[j * 68 + 64 + s] = ww;
        }
        __syncthreads();
        for (int j = 0; j < 128; ++j) {
            const float4* wp = (const float4*)&ws[j * 68 + sub * 16];
            float4 w0 = wp[0], w1 = wp[1], w2 = wp[2], w3 = wp[3];
            float dot = 0.f;
            dot = fmaf(z0.x,w0.x,dot); dot = fmaf(z0.y,w0.y,dot);
            dot = fmaf(z0.z,w0.z,dot); dot = fmaf(z0.w,w0.w,dot);
            dot = fmaf(z1.x,w1.x,dot); dot = fmaf(z1.y,w1.y,dot);
            dot = fmaf(z1.z,w1.z,dot); dot = fmaf(z1.w,w1.w,dot);
            dot = fmaf(z2.x,w2.x,dot); dot = fmaf(z2.y,w2.y,dot);
            dot = fmaf(z2.z,w2.z,dot); dot = fmaf(z2.w,w2.w,dot);
            dot = fmaf(z3.x,w3.x,dot); dot = fmaf(z3.y,w3.y,dot);
            dot = fmaf(z3.z,w3.z,dot); dot = fmaf(z3.w,w3.w,dot);
            float t = fmaf(dot, -2.f, ws[j * 68 + 64 + sub]);
            t += __shfl_xor(t, 1, 64);
            t += __shfl_xor(t, 2, 64);
            if (t < best) { best = t; bj = c0 + j; }
        }
    }

    float zz = zzp;
    zz += __shfl_xor(zz, 1, 64);
    zz += __shfl_xor(zz, 2, 64);

    if (sub == 0) {
        if (half) { d1[r] = zz + best; j1[r] = bj; }
        else      { d0[r] = zz + best; j0[r] = bj; }
    }
}

// VQ stage 2: combine halves, gather hq rows, accumulate loss.
__global__ __launch_bounds__(256)
void vq2_rF(const float* __restrict__ d0, const float* __restrict__ d1,
            const int* __restrict__ j0, const int* __restrict__ j1,
            const float* __restrict__ emb, float* __restrict__ hq,
            double* __restrict__ lossAcc)
{
    const int r = blockIdx.x * 256 + threadIdx.x;
    float da = d0[r], db = d1[r];
    bool pick1 = db < da;                    // ties -> half 0 (lower index)
    float d = pick1 ? db : da;
    int   j = pick1 ? j1[r] : j0[r];

    const float4* ep = (const float4*)(emb + (size_t)j * 64);
    float4* hp = (float4*)(hq + (size_t)r * 64);
#pragma unroll
    for (int t = 0; t < 16; ++t) hp[t] = ep[t];

    float s = d;
#pragma unroll
    for (int m = 1; m < 64; m <<= 1) s += __shfl_xor(s, m, 64);
    if ((threadIdx.x & 63) == 0) atomicAdd(lossAcc, (double)s);
}

__global__ void zd_rD(double* p, int n) {
    int i = blockIdx.x * 256 + threadIdx.x;
    if (i < n) p[i] = 0.0;
}

__global__ void wsguard_rD(float* p, int n) {
    int i = blockIdx.x * 256 + threadIdx.x;
    if (i < n) p[i] = 1000.0f;
}

__global__ void lossfin_rD(const double* acc, float* out) {
    float m = (float)(acc[0] * (1.0 / 32768.0));
    out[2097152] = m;   // commit_loss
    out[2097153] = m;   // vq_loss
}

extern "C" void kernel_launch(void* const* d_in, const int* in_sizes, int n_in,
                              void* d_out, int out_size, void* d_ws, size_t ws_size,
                              hipStream_t stream)
{
    const size_t NEED = (size_t)3 * 4194304 * 4 + 2305 * 8 + 1152 * 8 + 64;
    if (ws_size < NEED) {
        wsguard_rD<<<dim3((out_size + 255) / 256), 256, 0, stream>>>((float*)d_out, out_size);
        return;
    }

    const float* x        = (const float*)d_in[0];
    const float* w_conv   = (const float*)d_in[1];
    const float* b_conv   = (const float*)d_in[2];
    const float* g_conv   = (const float*)d_in[3];
    const float* be_conv  = (const float*)d_in[4];
    const float* w_r1     = (const float*)d_in[5];
    const float* b_r1     = (const float*)d_in[6];
    const float* g_r1     = (const float*)d_in[7];
    const float* be_r1    = (const float*)d_in[8];
    const float* w_ds1    = (const float*)d_in[9];
    const float* b_ds1    = (const float*)d_in[10];
    const float* w_r2     = (const float*)d_in[11];
    const float* b_r2     = (const float*)d_in[12];
    const float* g_r2     = (const float*)d_in[13];
    const float* be_r2    = (const float*)d_in[14];
    const float* w_1to2   = (const float*)d_in[15];
    const float* w_ds2    = (const float*)d_in[16];
    const float* b_ds2    = (const float*)d_in[17];
    const float* embed_w  = (const float*)d_in[18];
    const float* w_us2    = (const float*)d_in[19];
    const float* b_us2    = (const float*)d_in[20];
    const float* w_dr2    = (const float*)d_in[21];
    const float* b_dr2    = (const float*)d_in[22];
    const float* g_dr2    = (const float*)d_in[23];
    const float* be_dr2   = (const float*)d_in[24];
    const float* w_2to1   = (const float*)d_in[25];
    const float* w_us1    = (const float*)d_in[26];
    const float* b_us1    = (const float*)d_in[27];
    const float* w_dr1    = (const float*)d_in[28];
    const float* b_dr1    = (const float*)d_in[29];
    const float* g_dr1    = (const float*)d_in[30];
    const float* be_dr1   = (const float*)d_in[31];
    const float* w_deconv = (const float*)d_in[32];
    const float* b_deconv = (const float*)d_in[33];

    float* out = (float*)d_out;

    float*  B0 = (float*)d_ws;
    float*  B1 = B0 + 4194304;
    float*  B2 = B0 + 2 * 4194304;
    double* SD = (double*)(B0 + 3 * 4194304);
    double* lossAcc = SD + 9 * 256;

    // VQ scratch lives in B0 (free between ds2 and us2)
    float* vqd0 = B0;
    float* vqd1 = B0 + 32768;
    int*   vqj0 = (int*)(B0 + 65536);
    int*   vqj1 = (int*)(B0 + 98304);

    const int N = 64;
    const double i64k = 1.0 / 65536.0;
    const double i32k = 1.0 / 32768.0;
    const float*  NOF = nullptr;
    const double* NOD = nullptr;

    zd_rD<<<dim3(10), 256, 0, stream>>>(SD, 9 * 256 + 1);

    // ---- encoder ----
    conv_rP<32,64,7,0,128,32,4,3,2, F_BIAS|F_STATS>
        <<<dim3(4, N, 2), 256, 0, stream>>>(x, NOD, NOF, NOF, NOF, NOD, NOF, NOF,
            w_conv, b_conv, NOF, NOD, NOF, NOF, SD+0*256, B0,
            1024, 1024, 32, 32, 0.0, 0.0, 0.0);

    // r1#1..3: TL=256 (TLT=8, swizzled), NT=2 -> grid (2,N,2)=256 blocks
    conv_rP<64,64,3,0,256,32,4,1,2, F_BIAS|F_STATS|F_INBN>
        <<<dim3(2, N, 2), 256, 0, stream>>>(B0, SD+0*256, g_conv, be_conv,
            NOF, NOD, NOF, NOF, w_r1, b_r1, NOF, NOD, NOF, NOF, SD+1*256, B1,
            1024, 1024, 64, 64, i64k, 0.0, 0.0);

    conv_rP<64,64,3,0,256,32,4,1,2, F_BIAS|F_STATS|F_INBN|F_INRELU>
        <<<dim3(2, N, 2), 256, 0, stream>>>(B1, SD+1*256, g_r1, be_r1,
            NOF, NOD, NOF, NOF, w_r1+12288, b_r1+64, NOF, NOD, NOF, NOF, SD+2*256, B2,
            1024, 1024, 64, 64, i64k, 0.0, 0.0);

    conv_rP<64,64,3,0,256,32,4,1,2, F_BIAS|F_STATS|F_INBN|F_INRELU>
        <<<dim3(2, N, 2), 256, 0, stream>>>(B2, SD+2*256, g_r1+64, be_r1+64,
            NOF, NOD, NOF, NOF, w_r1+24576, b_r1+128, NOF, NOD, NOF, NOF, SD+3*256, B1,
            1024, 1024, 64, 64, i64k, 0.0, 0.0);

    // ds1: input = bn3(B1) + bn0(B0) -> stride-2 conv -> B2
    conv_rP<64,64,2,1,64,32,4,0,2, F_BIAS|F_INBN|F_INB|F_INBBN>
        <<<dim3(4, N, 2), 256, 0, stream>>>(B1, SD+3*256, g_r1+128, be_r1+128,
            B0, SD+0*256, g_conv, be_conv, w_ds1, b_ds1, NOF, NOD, NOF, NOF,
            nullptr, B2, 1024, 512, 64, 64, i64k, i64k, 0.0);

    conv_rP<64,128,3,0,128,32,4,1,2, F_BIAS|F_STATS>
        <<<dim3(2, N, 4), 256, 0, stream>>>(B2, NOD, NOF, NOF, NOF, NOD, NOF, NOF,
            w_r2, b_r2, NOF, NOD, NOF, NOF, SD+4*256, B1,
            512, 512, 64, 64, 0.0, 0.0, 0.0);

    // 1to2: conv(B2,w_1to2) + bn4(B1) -> B0  (w_1to2 is (O=128,I=64,K=1) -> wci=64)
    conv_rP<64,128,1,0,128,32,4,0,2, F_ADD|F_ADDBN>
        <<<dim3(2, N, 4), 256, 0, stream>>>(B2, NOD, NOF, NOF, NOF, NOD, NOF, NOF,
            w_1to2, NOF, B1, SD+4*256, g_r2, be_r2, nullptr, B0,
            512, 512, 64, 64, 0.0, 0.0, i32k);

    // ds2: B0 -> stride-2 conv -> B1
    conv_rP<128,128,2,1,32,32,4,0,2, F_BIAS>
        <<<dim3(4, N, 4), 256, 0, stream>>>(B0, NOD, NOF, NOF, NOF, NOD, NOF, NOF,
            w_ds2, b_ds2, NOF, NOD, NOF, NOF, nullptr, B1,
            512, 256, 128, 128, 0.0, 0.0, 0.0);

    // ---- vector quantization ----
    vq1_rF<<<dim3(1024), 256, 0, stream>>>(B1, embed_w, vqd0, vqd1, vqj0, vqj1);
    vq2_rF<<<dim3(128), 256, 0, stream>>>(vqd0, vqd1, vqj0, vqj1, embed_w, B2, lossAcc);
    lossfin_rD<<<1, 1, 0, stream>>>(lossAcc, out);

    // ---- decoder ----
    // us2: B2(hq) -> transposed stride-2 -> B0
    conv_rP<128,128,2,2,128,32,4,0,2, F_BIAS>
        <<<dim3(2, N, 4), 256, 0, stream>>>(B2, NOD, NOF, NOF, NOF, NOD, NOF, NOF,
            w_us2, b_us2, NOF, NOD, NOF, NOF, nullptr, B0,
            256, 512, 128, 128, 0.0, 0.0, 0.0);

    // dr2 (CI=128 split 2x64): a = ci 0..63 + bias -> B1 (512 blocks, NT=1)
    conv_rP<64,64,3,0,128,32,4,1,1, F_WT|F_BIAS>
        <<<dim3(4, N, 2), 256, 0, stream>>>(B0, NOD, NOF, NOF, NOF, NOD, NOF, NOF,
            w_dr2, b_dr2, NOF, NOD, NOF, NOF, nullptr, B1,
            512, 512, 128, 64, 0.0, 0.0, 0.0);
    conv_rP<64,64,3,0,128,32,4,1,1, F_WT|F_STATS|F_ADD>
        <<<dim3(4, N, 2), 256, 0, stream>>>(B0 + (size_t)64*512, NOD, NOF, NOF,
            NOF, NOD, NOF, NOF, w_dr2 + 64*64*3, NOF, B1, NOD, NOF, NOF,
            SD+5*256, B1, 512, 512, 128, 64, 0.0, 0.0, 0.0);

    // 2to1 (CI=128 split): a = conv(ci 0..63) + bn5(B1) -> B2 (512 blocks, NT=1)
    conv_rP<64,64,1,0,128,32,4,0,1, F_ADD|F_ADDBN>
        <<<dim3(4, N, 2), 256, 0, stream>>>(B0, NOD, NOF, NOF, NOF, NOD, NOF, NOF,
            w_2to1, NOF, B1, SD+5*256, g_dr2, be_dr2, nullptr, B2,
            512, 512, 128, 128, 0.0, 0.0, i32k);
    conv_rP<64,64,1,0,128,32,4,0,1, F_ADD>
        <<<dim3(4, N, 2), 256, 0, stream>>>(B0 + (size_t)64*512, NOD, NOF, NOF,
            NOF, NOD, NOF, NOF, w_2to1 + 64, NOF, B2, NOD, NOF, NOF,
            nullptr, B2, 512, 512, 128, 128, 0.0, 0.0, 0.0);

    // us1: B2 -> transposed stride-2 -> B0 (t, kept raw for final skip)
    conv_rP<64,64,2,2,128,32,4,0,2, F_BIAS>
        <<<dim3(4, N, 2), 256, 0, stream>>>(B2, NOD, NOF, NOF, NOF, NOD, NOF, NOF,
            w_us1, b_us1, NOF, NOD, NOF, NOF, nullptr, B0,
            512, 1024, 64, 64, 0.0, 0.0, 0.0);

    // dr1#1..3: TL=256 (TLT=8, swizzled), NT=2 -> grid (2,N,2)=256 blocks
    conv_rP<64,64,3,0,256,32,4,1,2, F_WT|F_BIAS|F_STATS>
        <<<dim3(2, N, 2), 256, 0, stream>>>(B0, NOD, NOF, NOF, NOF, NOD, NOF, NOF,
            w_dr1, b_dr1, NOF, NOD, NOF, NOF, SD+6*256, B1,
            1024, 1024, 64, 64, 0.0, 0.0, 0.0);

    conv_rP<64,64,3,0,256,32,4,1,2, F_WT|F_BIAS|F_STATS|F_INBN|F_INRELU>
        <<<dim3(2, N, 2), 256, 0, stream>>>(B1, SD+6*256, g_dr1, be_dr1,
            NOF, NOD, NOF, NOF, w_dr1+12288, b_dr1+64, NOF, NOD, NOF, NOF,
            SD+7*256, B2, 1024, 1024, 64, 64, i64k, 0.0, 0.0);

    conv_rP<64,64,3,0,256,32,4,1,2, F_WT|F_BIAS|F_STATS|F_INBN|F_INRELU>
        <<<dim3(2, N, 2), 256, 0, stream>>>(B2, SD+7*256, g_dr1+64, be_dr1+64,
            NOF, NOD, NOF, NOF, w_dr1+24576, b_dr1+128, NOF, NOD, NOF, NOF,
            SD+8*256, B1, 1024, 1024, 64, 64, i64k, 0.0, 0.0);

    // deconv: input = bn8(B1) + B0 raw -> convT K=7 -> out
    conv_rP<64,32,7,0,128,16,4,3,2, F_WT|F_BIAS|F_INBN|F_INB>
        <<<dim3(4, N, 2), 256, 0, stream>>>(B1, SD+8*256, g_dr1+128, be_dr1+128,
            B0, NOD, NOF, NOF, w_deconv, b_deconv, NOF, NOD, NOF, NOF,
            nullptr, out, 1024, 1024, 64, 64, i64k, 0.0, 0.0);
}